// Round 16
// baseline (568.958 us; speedup 1.0000x reference)
//
#include <hip/hip_runtime.h>
#include <math.h>

#define NP 16384      // pixels per map (128*128)
#define CH 256        // channels (K)
#define WDIM 128
#define EPSF 1e-8f

#define CHUNK 32
#define SPLITS 16
#define CPS (NP / SPLITS)            // 1024 cols per split
#define NCHUNK (CPS / CHUNK)         // 32
#define ROWS 512                     // rows per block (8 waves x 64)
#define NRT (NP / ROWS)              // 32 row tiles
#define CHUNK_BYTES (CHUNK * CH * 2) // 16384
#define NCOLSLOT (NRT * 3)           // 96 col-candidate slots per column
#define RKEYS (SPLITS * 3)           // 48 row-candidate keys per row

typedef short short8 __attribute__((ext_vector_type(8)));
typedef float floatx4 __attribute__((ext_vector_type(4)));

typedef __attribute__((address_space(1))) const unsigned int gu32;
typedef __attribute__((address_space(3))) unsigned int lu32;

#define NEG_INF_F __int_as_float(0xFF800000)
#define ROWKEY_MASK 0xFFFFFC00u      // 22-bit sim | 10-bit local col

// ------------------------------------------------------------------
// prep: per-pixel 1/||d||, fp32 normalized transposed [pix][256],
// bf16 normalized swizzled (element ch stored at ch ^ ((pix&7)<<3))
// ------------------------------------------------------------------
__global__ __launch_bounds__(256) void prep_kernel(
    const float* __restrict__ A, const float* __restrict__ B,
    float* __restrict__ AT, float* __restrict__ BT,
    unsigned short* __restrict__ Abf, unsigned short* __restrict__ Bbf)
{
    __shared__ float tile[64 * 257];
    __shared__ float rnv[64];
    const int bid = blockIdx.x;
    const float* __restrict__ src = (bid < 256) ? A : B;
    float* __restrict__ dstT = (bid < 256) ? AT : BT;
    unsigned short* __restrict__ dstb = (bid < 256) ? Abf : Bbf;
    const int pixBase = (bid & 255) * 64;
    const int t = threadIdx.x;

    for (int k = 0; k < 64 * 256; k += 256) {
        int idx = k + t;
        int p = idx & 63;
        int c = idx >> 6;
        tile[p * 257 + c] = src[(size_t)c * NP + pixBase + p];
    }
    __syncthreads();
    if (t < 64) {
        float s = 0.f;
        for (int c = 0; c < 256; ++c) { float v = tile[t * 257 + c]; s = fmaf(v, v, s); }
        rnv[t] = 1.0f / sqrtf(s);
    }
    __syncthreads();
    for (int k = 0; k < 64 * 256; k += 256) {
        int idx = k + t;
        int p = idx >> 8;
        int c = idx & 255;
        dstT[((size_t)(pixBase + p) << 8) + c] = tile[p * 257 + c] * rnv[p];
    }
    for (int k = 0; k < 64 * 128; k += 256) {
        int idx = k + t;
        int p = idx >> 7;
        int c2 = (idx & 127) * 2;
        float rn = rnv[p];
        float v0 = tile[p * 257 + c2] * rn;
        float v1 = tile[p * 257 + c2 + 1] * rn;
        unsigned u0 = __float_as_uint(v0); u0 = (u0 + 0x7fffu + ((u0 >> 16) & 1u)) >> 16;
        unsigned u1 = __float_as_uint(v1); u1 = (u1 + 0x7fffu + ((u1 >> 16) & 1u)) >> 16;
        unsigned sw = ((unsigned)(p & 7)) << 3;
        int e = ((pixBase + p) << 8) + (c2 ^ (int)sw);
        *(unsigned*)(dstb + e) = (u0 & 0xffffu) | (u1 << 16);
    }
}

// ------------------------------------------------------------------
// simk ONE-PASS, 512-row blocks, SPLITS=16 -> grid 512 = 2 blocks/CU
// = 4 waves/SIMD (R15 had 1 block/CU; latency-stall plateau).
// Total staging traffic is SPLITS-invariant; per-sim cost unchanged.
// Per chunk: STAGE(c+1) | MERGE2(c-1) | 64 MFMA | col extract ->
// wave-private cbw (same-wave DS in-order, no barrier) -> 2 lanes/col
// top-2 of 16 -> colwave dbuf -> deferred MERGE2: block top-3/col.
// Rows (A) = B-operand in regs (pinned). cand_row = raw 22|10 keys.
// ------------------------------------------------------------------
__global__ __launch_bounds__(512, 4) void simk_kernel(
    const unsigned short* __restrict__ Abf, const unsigned short* __restrict__ Bbf,
    unsigned* __restrict__ cand_row, unsigned* __restrict__ cand_col)
{
    __shared__ __align__(16) char smem[2 * CHUNK_BYTES];      // 32 KB staging
    __shared__ __align__(16) float2 cbw[8][32 * 17];          // 34 KB wave-private
    __shared__ __align__(16) float2 colwave[2][32][17];       // 8.7 KB dbuf
    const int bid = blockIdx.x;
    const int rt = bid >> 4;          // 0..31
    const int split = bid & 15;       // 0..15
    const int t = threadIdx.x;        // 0..511
    const int w = t >> 6;             // 0..7
    const int l = t & 63;
    const int l15 = l & 15, lhi = l >> 4;
    const int rowBase = rt * ROWS;
    const int colBase = split * CPS;

    // --- row-descriptor fragments (B-operand) from A, pinned ---
    short8 Bfr[4][8];
#pragma unroll
    for (int ni = 0; ni < 4; ++ni) {
        int pix = rowBase + w * 64 + ni * 16 + l15;
        const unsigned short* pr = Abf + ((size_t)pix << 8);
        int sw = (pix & 7) << 3;
#pragma unroll
        for (int kk = 0; kk < 8; ++kk) {
            int ke = kk * 32 + lhi * 8;
            Bfr[ni][kk] = *(const short8*)(pr + (ke ^ sw));
        }
    }
#pragma unroll
    for (int ni = 0; ni < 4; ++ni)
#pragma unroll
        for (int kk = 0; kk < 8; ++kk)
            asm volatile("" : "+v"(Bfr[ni][kk]));

    // --- LDS byte offsets for A-operand frags (mi=0; mi=1 is +8192) ---
    int aoff[8];
    {
        int cp = l15;
        int sw = (cp & 7) << 3;
#pragma unroll
        for (int kk = 0; kk < 8; ++kk) {
            int ke = kk * 32 + lhi * 8;
            aoff[kk] = (cp * 256 + (ke ^ sw)) * 2;
        }
    }

    // row running top-2 per (mi, ni) stream — split by mi for ILP
    float tv0[2][4], tv1[2][4];
#pragma unroll
    for (int mi = 0; mi < 2; ++mi)
#pragma unroll
        for (int ni = 0; ni < 4; ++ni) { tv0[mi][ni] = NEG_INF_F; tv1[mi][ni] = NEG_INF_F; }

    const char* gbase = (const char*)(Bbf + ((size_t)colBase << 8));
    const floatx4 fzero = {0.f, 0.f, 0.f, 0.f};
    floatx4 acc[2][4];

#define STAGE(CIDX, BUFSEL) do {                                              \
        const char* gsrc_ = gbase + (size_t)(CIDX) * CHUNK_BYTES;             \
        char* bdst_ = smem + (BUFSEL) * CHUNK_BYTES;                          \
        _Pragma("unroll")                                                     \
        for (int r_ = 0; r_ < 2; ++r_) {                                      \
            int off_ = w * 2048 + r_ * 1024;                                  \
            __builtin_amdgcn_global_load_lds((gu32*)(gsrc_ + off_ + l * 16),  \
                                             (lu32*)(bdst_ + off_), 16, 0, 0);\
        }                                                                     \
    } while (0)

#define MERGE2(CIDX) do {                                                     \
        if (t < 32) {                                                         \
            float b0_ = NEG_INF_F, b1_ = NEG_INF_F, b2_ = NEG_INF_F;          \
            _Pragma("unroll")                                                 \
            for (int j_ = 0; j_ < 16; ++j_) {                                 \
                float2 v_ = colwave[(CIDX) & 1][t][j_];                       \
                float k_ = v_.x, h_;                                          \
                h_ = fmaxf(b0_, k_); k_ = fminf(b0_, k_); b0_ = h_;           \
                h_ = fmaxf(b1_, k_); k_ = fminf(b1_, k_); b1_ = h_;           \
                b2_ = fmaxf(b2_, k_);                                         \
                k_ = v_.y;                                                    \
                h_ = fmaxf(b0_, k_); k_ = fminf(b0_, k_); b0_ = h_;           \
                h_ = fmaxf(b1_, k_); k_ = fminf(b1_, k_); b1_ = h_;           \
                b2_ = fmaxf(b2_, k_);                                         \
            }                                                                 \
            int colG_ = colBase + (CIDX) * 32 + t;                            \
            cand_col[(size_t)(rt * 3 + 0) * NP + colG_] = __float_as_uint(b0_);\
            cand_col[(size_t)(rt * 3 + 1) * NP + colG_] = __float_as_uint(b1_);\
            cand_col[(size_t)(rt * 3 + 2) * NP + colG_] = __float_as_uint(b2_);\
        }                                                                     \
    } while (0)

    STAGE(0, 0);

    for (int c = 0; c < NCHUNK; ++c) {
        __syncthreads();   // B1: staging(c) ready; colwave[(c-1)&1] published
        if (c + 1 < NCHUNK) STAGE(c + 1, (c + 1) & 1);
        if (c > 0) MERGE2(c - 1);

        // ---- COMPUTE: 64 MFMA into acc ----
        {
            const char* buf = smem + (c & 1) * CHUNK_BYTES;
            __builtin_amdgcn_s_setprio(1);
            {
                short8 a0 = *(const short8*)(buf + aoff[0]);
                short8 a1 = *(const short8*)(buf + aoff[0] + 8192);
#pragma unroll
                for (int ni = 0; ni < 4; ++ni) {
                    acc[0][ni] = __builtin_amdgcn_mfma_f32_16x16x32_bf16(a0, Bfr[ni][0], fzero, 0, 0, 0);
                    acc[1][ni] = __builtin_amdgcn_mfma_f32_16x16x32_bf16(a1, Bfr[ni][0], fzero, 0, 0, 0);
                }
            }
#pragma unroll
            for (int kk = 1; kk < 8; ++kk) {
                short8 a0 = *(const short8*)(buf + aoff[kk]);
                short8 a1 = *(const short8*)(buf + aoff[kk] + 8192);
#pragma unroll
                for (int ni = 0; ni < 4; ++ni) {
                    acc[0][ni] = __builtin_amdgcn_mfma_f32_16x16x32_bf16(a0, Bfr[ni][kk], acc[0][ni], 0, 0, 0);
                    acc[1][ni] = __builtin_amdgcn_mfma_f32_16x16x32_bf16(a1, Bfr[ni][kk], acc[1][ni], 0, 0, 0);
                }
            }
            __builtin_amdgcn_s_setprio(0);
        }

        // ---- COL extract: per-lane sorted pair of 4 rows -> cbw[w] ----
        {
            const unsigned brb = ((unsigned)w << 6) | (unsigned)l15;
#pragma unroll
            for (int mi = 0; mi < 2; ++mi) {
#pragma unroll
                for (int reg = 0; reg < 4; ++reg) {
                    unsigned k0 = (__float_as_uint(acc[mi][0][reg]) & 0xFFFFFE00u) | brb;
                    unsigned k1 = (__float_as_uint(acc[mi][1][reg]) & 0xFFFFFE00u) | (brb | 16u);
                    unsigned k2 = (__float_as_uint(acc[mi][2][reg]) & 0xFFFFFE00u) | (brb | 32u);
                    unsigned k3 = (__float_as_uint(acc[mi][3][reg]) & 0xFFFFFE00u) | (brb | 48u);
                    float f0 = __uint_as_float(k0), f1 = __uint_as_float(k1);
                    float f2 = __uint_as_float(k2), f3 = __uint_as_float(k3);
                    float h01 = fmaxf(f0, f1), l01 = fminf(f0, f1);
                    float h23 = fmaxf(f2, f3), l23 = fminf(f2, f3);
                    float hi = fmaxf(h01, h23);
                    float lo = fmaxf(fminf(h01, h23), fmaxf(l01, l23));
                    int colL = mi * 16 + lhi * 4 + reg;
                    cbw[w][colL * 17 + l15] = make_float2(hi, lo);
                }
            }
        }

        // ---- ROW top-2 (22-bit key | c*32 + col-local), mi-split chains ----
        {
            const int cS = c << 5;
#pragma unroll
            for (int mi = 0; mi < 2; ++mi) {
#pragma unroll
                for (int reg = 0; reg < 4; ++reg) {
                    const int ib = (lhi * 4 + mi * 16 + reg) | cS;
#pragma unroll
                    for (int ni = 0; ni < 4; ++ni) {
                        int kb = (__float_as_int(acc[mi][ni][reg]) & (int)ROWKEY_MASK) | ib;
                        float fk = __int_as_float(kb);
                        float h = fmaxf(tv0[mi][ni], fk);
                        float lo2 = fminf(tv0[mi][ni], fk);
                        tv0[mi][ni] = h;
                        tv1[mi][ni] = fmaxf(tv1[mi][ni], lo2);
                    }
                }
            }
        }

        // ---- wave merge (no barrier: same-wave DS ops are in-order):
        //      2 lanes/col read 8 pairs each -> top-2 of 16 -> colwave ----
        {
            int colR = l >> 1, half = l & 1;
            const float2* src = &cbw[w][colR * 17 + half * 8];
            float a = NEG_INF_F, b = NEG_INF_F;
#pragma unroll
            for (int j = 0; j < 8; ++j) {
                float2 v = src[j];
                float t0 = fmaxf(a, v.x);
                float t1 = fmaxf(fminf(a, v.x), fmaxf(b, v.y));
                a = t0; b = t1;
            }
            colwave[c & 1][colR][w * 2 + half] = make_float2(a, b);
        }
    }
    __syncthreads();       // publishes colwave[(NCHUNK-1)&1]; cbw free
    MERGE2(NCHUNK - 1);
#undef STAGE
#undef MERGE2

    // ---- final row merge: 16 keys per row -> top-3 keys per split ----
    int4* mrg = (int4*)cbw;        // [512 rows][4 lhi] int4 = 32 KB (cbw is 34)
#pragma unroll
    for (int ni = 0; ni < 4; ++ni) {
        int rloc = w * 64 + ni * 16 + l15;
        int4 p;
        p.x = __float_as_int(tv0[0][ni]);
        p.y = __float_as_int(tv1[0][ni]);
        p.z = __float_as_int(tv0[1][ni]);
        p.w = __float_as_int(tv1[1][ni]);
        mrg[rloc * 4 + lhi] = p;
    }
    __syncthreads();
    {
        float b0 = NEG_INF_F, b1 = NEG_INF_F, b2 = NEG_INF_F;
#pragma unroll
        for (int q = 0; q < 4; ++q) {
            int4 p = mrg[t * 4 + q];
            int ks[4] = {p.x, p.y, p.z, p.w};
#pragma unroll
            for (int j = 0; j < 4; ++j) {
                float k = __int_as_float(ks[j]), h;
                h = fmaxf(b0, k); k = fminf(b0, k); b0 = h;
                h = fmaxf(b1, k); k = fminf(b1, k); b1 = h;
                b2 = fmaxf(b2, k);
            }
        }
        int rowG = rowBase + t;
        unsigned* o = cand_row + (size_t)rowG * RKEYS + split * 3;
        o[0] = __float_as_uint(b0);
        o[1] = __float_as_uint(b1);
        o[2] = __float_as_uint(b2);
    }
}

// ------------------------------------------------------------------
// mergecol: per column, key top-6 of 96 block partials -> rows
// ------------------------------------------------------------------
__global__ __launch_bounds__(256) void mergecol_kernel(
    const unsigned* __restrict__ cand_col, int* __restrict__ col6)
{
    int col = blockIdx.x * 256 + threadIdx.x;   // 0..16383
    float bv0 = NEG_INF_F, bv1 = NEG_INF_F, bv2 = NEG_INF_F;
    float bv3 = NEG_INF_F, bv4 = NEG_INF_F, bv5 = NEG_INF_F;
    for (int s = 0; s < NCOLSLOT; ++s) {
        float k = __uint_as_float(cand_col[(size_t)s * NP + col]);
        float h;
        h = fmaxf(bv0, k); k = fminf(bv0, k); bv0 = h;
        h = fmaxf(bv1, k); k = fminf(bv1, k); bv1 = h;
        h = fmaxf(bv2, k); k = fminf(bv2, k); bv2 = h;
        h = fmaxf(bv3, k); k = fminf(bv3, k); bv3 = h;
        h = fmaxf(bv4, k); k = fminf(bv4, k); bv4 = h;
        bv5 = fmaxf(bv5, k);
    }
    const float thr = bv5;
    int r0 = 0, r1 = 0, r2 = 0, r3 = 0, r4 = 0, r5 = 0;
    int cnt = 0;
    for (int s = 0; s < NCOLSLOT; ++s) {
        unsigned ku = cand_col[(size_t)s * NP + col];
        float k = __uint_as_float(ku);
        bool take = (k >= thr) && (cnt < 6);
        int row = (s / 3) * ROWS + (int)(ku & 0x1FFu);
        r0 = (take && cnt == 0) ? row : r0;
        r1 = (take && cnt == 1) ? row : r1;
        r2 = (take && cnt == 2) ? row : r2;
        r3 = (take && cnt == 3) ? row : r3;
        r4 = (take && cnt == 4) ? row : r4;
        r5 = (take && cnt == 5) ? row : r5;
        cnt += take ? 1 : 0;
    }
    int* o = col6 + (size_t)col * 6;
    o[0] = r0; o[1] = r1; o[2] = r2; o[3] = r3; o[4] = r4; o[5] = r5;
}

// ------------------------------------------------------------------
// rescore_row: key-threshold top-8 of 48, then exact fp32 top-2
// (wave per row; branch is wave-uniform)
// ------------------------------------------------------------------
__global__ __launch_bounds__(256) void rescore_row_kernel(
    const float* __restrict__ AT, const float* __restrict__ BT,
    const unsigned* __restrict__ cand_row, float4* __restrict__ final12)
{
    const int t = threadIdx.x;
    const int w = t >> 6, l = t & 63;
    const int row = blockIdx.x * 4 + w;    // 0..16383
    float4 rv = *(const float4*)(AT + ((size_t)row << 8) + l * 4);
    const unsigned* __restrict__ cl = cand_row + (size_t)row * RKEYS;

    // 8th-largest key (all lanes compute identically from broadcast loads)
    float t8[8];
#pragma unroll
    for (int q = 0; q < 8; ++q) t8[q] = NEG_INF_F;
#pragma unroll 4
    for (int s = 0; s < RKEYS; ++s) {
        float k = __uint_as_float(cl[s]);
#pragma unroll
        for (int q = 0; q < 8; ++q) {
            float h = fmaxf(t8[q], k);
            k = fminf(t8[q], k);
            t8[q] = h;
        }
    }
    const float thr = t8[7];

    float v0 = -4.f, v1 = -4.f; int i0 = 0x7fffffff, i1 = 0x7fffffff;
    int taken = 0;
    for (int s = 0; s < RKEYS; ++s) {
        unsigned ku = cl[s];
        float kf = __uint_as_float(ku);
        if (kf >= thr && taken < 8) {      // wave-uniform
            ++taken;
            int idx = (s / 3) * CPS + (int)(ku & 0x3FFu);
            float4 cv = *(const float4*)(BT + ((size_t)idx << 8) + l * 4);
            float d = rv.x * cv.x;
            d = fmaf(rv.y, cv.y, d);
            d = fmaf(rv.z, cv.z, d);
            d = fmaf(rv.w, cv.w, d);
#pragma unroll
            for (int m = 1; m < 64; m <<= 1) d += __shfl_xor(d, m, 64);
            if (d > v0 || (d == v0 && idx < i0)) {
                v1 = v0; i1 = i0; v0 = d; i0 = idx;
            } else if (d > v1 || (d == v1 && idx < i1)) {
                v1 = d; i1 = idx;
            }
        }
    }
    if (l == 0) {
        float4 r; r.x = v0; r.y = v1;
        r.z = __int_as_float(i0); r.w = __int_as_float(i1);
        final12[row] = r;
    }
}

// ------------------------------------------------------------------
// rescore_col: exact fp32 top-2 over 6 cands per column (wave per col)
// ------------------------------------------------------------------
__global__ __launch_bounds__(256) void rescore_col_kernel(
    const float* __restrict__ AT, const float* __restrict__ BT,
    const int* __restrict__ col6,
    int* __restrict__ nn21, float* __restrict__ ratio21)
{
    const int t = threadIdx.x;
    const int w = t >> 6, l = t & 63;
    const int col = blockIdx.x * 4 + w;    // 0..16383
    float4 rv = *(const float4*)(BT + ((size_t)col << 8) + l * 4);
    float v0 = -4.f, v1 = -4.f; int i0 = 0x7fffffff, i1 = 0x7fffffff;
    const int* __restrict__ cl = col6 + (size_t)col * 6;
#pragma unroll
    for (int j = 0; j < 6; ++j) {
        int idx = cl[j];
        float4 cv = *(const float4*)(AT + ((size_t)idx << 8) + l * 4);
        float d = rv.x * cv.x;
        d = fmaf(rv.y, cv.y, d);
        d = fmaf(rv.z, cv.z, d);
        d = fmaf(rv.w, cv.w, d);
#pragma unroll
        for (int m = 1; m < 64; m <<= 1) d += __shfl_xor(d, m, 64);
        if (d > v0 || (d == v0 && idx < i0)) {
            v1 = v0; i1 = i0; v0 = d; i0 = idx;
        } else if (d > v1 || (d == v1 && idx < i1)) {
            v1 = d; i1 = idx;
        }
    }
    if (l == 0) {
        nn21[col] = i0;
        float d0 = sqrtf(fmaxf(2.f - 2.f * v0, 1e-12f));
        float d1 = sqrtf(fmaxf(2.f - 2.f * v1, 1e-12f));
        ratio21[col] = d0 / (d1 + EPSF);
    }
}

// ------------------------------------------------------------------
// final: mutual check, ratio test, border mask
// ------------------------------------------------------------------
__global__ void final_kernel(const float4* __restrict__ final12,
                             const int* __restrict__ nn21,
                             const float* __restrict__ ratio21,
                             float* __restrict__ out) {
    int i = blockIdx.x * blockDim.x + threadIdx.x;  // 0..16383
    float4 a = final12[i];
    float d0 = sqrtf(fmaxf(2.f - 2.f * a.x, 1e-12f));
    float d1 = sqrtf(fmaxf(2.f - 2.f * a.y, 1e-12f));
    int nn = __float_as_int(a.z);
    float r12 = d0 / (d1 + EPSF);
    bool mutual = (nn21[nn] == i);
    float r = fmaxf(r12, ratio21[nn]);
    int xA = i & (WDIM - 1), yA = i >> 7;
    int xB = nn & (WDIM - 1), yB = nn >> 7;
    bool border = (xA == 0) || (xA == WDIM - 1) || (yA == 0) || (yA == WDIM - 1) ||
                  (xB == 0) || (xB == WDIM - 1) || (yB == 0) || (yB == WDIM - 1);
    bool valid = mutual && (r < 0.95f) && !border;
    out[2 * i]       = valid ? d0 : 0.f;
    out[2 * i + 1]   = valid ? d1 : 0.f;
    out[2 * NP + i]  = (float)nn;
    out[3 * NP + i]  = valid ? 1.f : 0.f;
}

extern "C" void kernel_launch(void* const* d_in, const int* in_sizes, int n_in,
                              void* d_out, int out_size, void* d_ws, size_t ws_size,
                              hipStream_t stream) {
    (void)in_sizes; (void)n_in; (void)out_size; (void)ws_size;
    const float* A = (const float*)d_in[0];
    const float* B = (const float*)d_in[1];
    float* out = (float*)d_out;

    char* ws = (char*)d_ws;
    float* AT = (float*)ws;                                          // 16 MB
    float* BT = AT + (size_t)NP * CH;                                // 16 MB
    unsigned short* Abf = (unsigned short*)(BT + (size_t)NP * CH);   // 8 MB
    unsigned short* Bbf = Abf + (size_t)NP * CH;                     // 8 MB
    unsigned* cand_row = (unsigned*)(Bbf + (size_t)NP * CH);         // 3 MB
    unsigned* cand_col = cand_row + (size_t)NP * RKEYS;              // 6.3 MB
    int* col6 = (int*)(cand_col + (size_t)NCOLSLOT * NP);            // 0.4 MB
    float4* final12 = (float4*)(col6 + (size_t)NP * 6);              // 256 KB
    int* nn21 = (int*)(final12 + NP);                                // 64 KB
    float* ratio21 = (float*)(nn21 + NP);                            // 64 KB

    prep_kernel<<<512, 256, 0, stream>>>(A, B, AT, BT, Abf, Bbf);
    simk_kernel<<<NRT * SPLITS, 512, 0, stream>>>(Abf, Bbf, cand_row, cand_col);
    mergecol_kernel<<<NP / 256, 256, 0, stream>>>(cand_col, col6);
    rescore_row_kernel<<<NP / 4, 256, 0, stream>>>(AT, BT, cand_row, final12);
    rescore_col_kernel<<<NP / 4, 256, 0, stream>>>(AT, BT, col6, nn21, ratio21);
    final_kernel<<<NP / 256, 256, 0, stream>>>(final12, nn21, ratio21, out);
}

// Round 17
// 289.339 us; speedup vs baseline: 1.9664x; 1.9664x over previous
//
#include <hip/hip_runtime.h>
#include <math.h>

#define NP 16384      // pixels per map (128*128)
#define CH 256        // channels (K)
#define WDIM 128
#define EPSF 1e-8f

#define CHUNK 32
#define SPLITS 16
#define CPS (NP / SPLITS)            // 1024 cols per split
#define NCHUNK (CPS / CHUNK)         // 32
#define ROWS 512                     // rows per block (8 waves x 64)
#define NRT (NP / ROWS)              // 32 row tiles
#define CHUNK_BYTES (CHUNK * CH * 2) // 16384
#define NCOLSLOT (NRT * 3)           // 96 col-candidate slots per column
#define RKEYS (SPLITS * 3)           // 48 row-candidate keys per row

typedef short short8 __attribute__((ext_vector_type(8)));
typedef float floatx4 __attribute__((ext_vector_type(4)));

typedef __attribute__((address_space(1))) const unsigned int gu32;
typedef __attribute__((address_space(3))) unsigned int lu32;

#define NEG_INF_F __int_as_float(0xFF800000)
#define ROWKEY_MASK 0xFFFFFC00u      // 22-bit sim | 10-bit local col

// ------------------------------------------------------------------
// prep: per-pixel 1/||d||, fp32 normalized transposed [pix][256],
// bf16 normalized swizzled (element ch stored at ch ^ ((pix&7)<<3))
// ------------------------------------------------------------------
__global__ __launch_bounds__(256) void prep_kernel(
    const float* __restrict__ A, const float* __restrict__ B,
    float* __restrict__ AT, float* __restrict__ BT,
    unsigned short* __restrict__ Abf, unsigned short* __restrict__ Bbf)
{
    __shared__ float tile[64 * 257];
    __shared__ float rnv[64];
    const int bid = blockIdx.x;
    const float* __restrict__ src = (bid < 256) ? A : B;
    float* __restrict__ dstT = (bid < 256) ? AT : BT;
    unsigned short* __restrict__ dstb = (bid < 256) ? Abf : Bbf;
    const int pixBase = (bid & 255) * 64;
    const int t = threadIdx.x;

    for (int k = 0; k < 64 * 256; k += 256) {
        int idx = k + t;
        int p = idx & 63;
        int c = idx >> 6;
        tile[p * 257 + c] = src[(size_t)c * NP + pixBase + p];
    }
    __syncthreads();
    if (t < 64) {
        float s = 0.f;
        for (int c = 0; c < 256; ++c) { float v = tile[t * 257 + c]; s = fmaf(v, v, s); }
        rnv[t] = 1.0f / sqrtf(s);
    }
    __syncthreads();
    for (int k = 0; k < 64 * 256; k += 256) {
        int idx = k + t;
        int p = idx >> 8;
        int c = idx & 255;
        dstT[((size_t)(pixBase + p) << 8) + c] = tile[p * 257 + c] * rnv[p];
    }
    for (int k = 0; k < 64 * 128; k += 256) {
        int idx = k + t;
        int p = idx >> 7;
        int c2 = (idx & 127) * 2;
        float rn = rnv[p];
        float v0 = tile[p * 257 + c2] * rn;
        float v1 = tile[p * 257 + c2 + 1] * rn;
        unsigned u0 = __float_as_uint(v0); u0 = (u0 + 0x7fffu + ((u0 >> 16) & 1u)) >> 16;
        unsigned u1 = __float_as_uint(v1); u1 = (u1 + 0x7fffu + ((u1 >> 16) & 1u)) >> 16;
        unsigned sw = ((unsigned)(p & 7)) << 3;
        int e = ((pixBase + p) << 8) + (c2 ^ (int)sw);
        *(unsigned*)(dstb + e) = (u0 & 0xffffu) | (u1 << 16);
    }
}

// ------------------------------------------------------------------
// simk ONE-PASS, 512-row blocks, SPLITS=16 -> grid 512 = 2 blocks/CU
// = 4 waves/SIMD. __launch_bounds__(512,2): do NOT force a 128-VGPR
// cap (R16 bug: (512,4) -> 64-VGPR alloc -> Bfr spilled to scratch ->
// 1.5 GB FETCH). At the natural 112 VGPR, 4 waves/SIMD (448<=512) and
// LDS 76.3KB x2 <= 160KB both fit -> 2 blocks/CU happens naturally.
// Per chunk: STAGE(c+1) | MERGE2(c-1) | 64 MFMA | col extract ->
// wave-private cbw (same-wave DS in-order, no barrier) -> 2 lanes/col
// top-2 of 16 -> colwave dbuf -> deferred MERGE2: block top-3/col.
// Rows (A) = B-operand in regs (pinned). cand_row = raw 22|10 keys.
// ------------------------------------------------------------------
__global__ __launch_bounds__(512, 2) void simk_kernel(
    const unsigned short* __restrict__ Abf, const unsigned short* __restrict__ Bbf,
    unsigned* __restrict__ cand_row, unsigned* __restrict__ cand_col)
{
    __shared__ __align__(16) char smem[2 * CHUNK_BYTES];      // 32 KB staging
    __shared__ __align__(16) float2 cbw[8][32 * 17];          // 34 KB wave-private
    __shared__ __align__(16) float2 colwave[2][32][17];       // 8.7 KB dbuf
    const int bid = blockIdx.x;
    const int rt = bid >> 4;          // 0..31
    const int split = bid & 15;       // 0..15
    const int t = threadIdx.x;        // 0..511
    const int w = t >> 6;             // 0..7
    const int l = t & 63;
    const int l15 = l & 15, lhi = l >> 4;
    const int rowBase = rt * ROWS;
    const int colBase = split * CPS;

    // --- row-descriptor fragments (B-operand) from A, pinned ---
    short8 Bfr[4][8];
#pragma unroll
    for (int ni = 0; ni < 4; ++ni) {
        int pix = rowBase + w * 64 + ni * 16 + l15;
        const unsigned short* pr = Abf + ((size_t)pix << 8);
        int sw = (pix & 7) << 3;
#pragma unroll
        for (int kk = 0; kk < 8; ++kk) {
            int ke = kk * 32 + lhi * 8;
            Bfr[ni][kk] = *(const short8*)(pr + (ke ^ sw));
        }
    }
#pragma unroll
    for (int ni = 0; ni < 4; ++ni)
#pragma unroll
        for (int kk = 0; kk < 8; ++kk)
            asm volatile("" : "+v"(Bfr[ni][kk]));

    // --- LDS byte offsets for A-operand frags (mi=0; mi=1 is +8192) ---
    int aoff[8];
    {
        int cp = l15;
        int sw = (cp & 7) << 3;
#pragma unroll
        for (int kk = 0; kk < 8; ++kk) {
            int ke = kk * 32 + lhi * 8;
            aoff[kk] = (cp * 256 + (ke ^ sw)) * 2;
        }
    }

    // row running top-2 per (mi, ni) stream — split by mi for ILP
    float tv0[2][4], tv1[2][4];
#pragma unroll
    for (int mi = 0; mi < 2; ++mi)
#pragma unroll
        for (int ni = 0; ni < 4; ++ni) { tv0[mi][ni] = NEG_INF_F; tv1[mi][ni] = NEG_INF_F; }

    const char* gbase = (const char*)(Bbf + ((size_t)colBase << 8));
    const floatx4 fzero = {0.f, 0.f, 0.f, 0.f};
    floatx4 acc[2][4];

#define STAGE(CIDX, BUFSEL) do {                                              \
        const char* gsrc_ = gbase + (size_t)(CIDX) * CHUNK_BYTES;             \
        char* bdst_ = smem + (BUFSEL) * CHUNK_BYTES;                          \
        _Pragma("unroll")                                                     \
        for (int r_ = 0; r_ < 2; ++r_) {                                      \
            int off_ = w * 2048 + r_ * 1024;                                  \
            __builtin_amdgcn_global_load_lds((gu32*)(gsrc_ + off_ + l * 16),  \
                                             (lu32*)(bdst_ + off_), 16, 0, 0);\
        }                                                                     \
    } while (0)

#define MERGE2(CIDX) do {                                                     \
        if (t < 32) {                                                         \
            float b0_ = NEG_INF_F, b1_ = NEG_INF_F, b2_ = NEG_INF_F;          \
            _Pragma("unroll")                                                 \
            for (int j_ = 0; j_ < 16; ++j_) {                                 \
                float2 v_ = colwave[(CIDX) & 1][t][j_];                       \
                float k_ = v_.x, h_;                                          \
                h_ = fmaxf(b0_, k_); k_ = fminf(b0_, k_); b0_ = h_;           \
                h_ = fmaxf(b1_, k_); k_ = fminf(b1_, k_); b1_ = h_;           \
                b2_ = fmaxf(b2_, k_);                                         \
                k_ = v_.y;                                                    \
                h_ = fmaxf(b0_, k_); k_ = fminf(b0_, k_); b0_ = h_;           \
                h_ = fmaxf(b1_, k_); k_ = fminf(b1_, k_); b1_ = h_;           \
                b2_ = fmaxf(b2_, k_);                                         \
            }                                                                 \
            int colG_ = colBase + (CIDX) * 32 + t;                            \
            cand_col[(size_t)(rt * 3 + 0) * NP + colG_] = __float_as_uint(b0_);\
            cand_col[(size_t)(rt * 3 + 1) * NP + colG_] = __float_as_uint(b1_);\
            cand_col[(size_t)(rt * 3 + 2) * NP + colG_] = __float_as_uint(b2_);\
        }                                                                     \
    } while (0)

    STAGE(0, 0);

    for (int c = 0; c < NCHUNK; ++c) {
        __syncthreads();   // B1: staging(c) ready; colwave[(c-1)&1] published
        if (c + 1 < NCHUNK) STAGE(c + 1, (c + 1) & 1);
        if (c > 0) MERGE2(c - 1);

        // ---- COMPUTE: 64 MFMA into acc ----
        {
            const char* buf = smem + (c & 1) * CHUNK_BYTES;
            __builtin_amdgcn_s_setprio(1);
            {
                short8 a0 = *(const short8*)(buf + aoff[0]);
                short8 a1 = *(const short8*)(buf + aoff[0] + 8192);
#pragma unroll
                for (int ni = 0; ni < 4; ++ni) {
                    acc[0][ni] = __builtin_amdgcn_mfma_f32_16x16x32_bf16(a0, Bfr[ni][0], fzero, 0, 0, 0);
                    acc[1][ni] = __builtin_amdgcn_mfma_f32_16x16x32_bf16(a1, Bfr[ni][0], fzero, 0, 0, 0);
                }
            }
#pragma unroll
            for (int kk = 1; kk < 8; ++kk) {
                short8 a0 = *(const short8*)(buf + aoff[kk]);
                short8 a1 = *(const short8*)(buf + aoff[kk] + 8192);
#pragma unroll
                for (int ni = 0; ni < 4; ++ni) {
                    acc[0][ni] = __builtin_amdgcn_mfma_f32_16x16x32_bf16(a0, Bfr[ni][kk], acc[0][ni], 0, 0, 0);
                    acc[1][ni] = __builtin_amdgcn_mfma_f32_16x16x32_bf16(a1, Bfr[ni][kk], acc[1][ni], 0, 0, 0);
                }
            }
            __builtin_amdgcn_s_setprio(0);
        }

        // ---- COL extract: per-lane sorted pair of 4 rows -> cbw[w] ----
        {
            const unsigned brb = ((unsigned)w << 6) | (unsigned)l15;
#pragma unroll
            for (int mi = 0; mi < 2; ++mi) {
#pragma unroll
                for (int reg = 0; reg < 4; ++reg) {
                    unsigned k0 = (__float_as_uint(acc[mi][0][reg]) & 0xFFFFFE00u) | brb;
                    unsigned k1 = (__float_as_uint(acc[mi][1][reg]) & 0xFFFFFE00u) | (brb | 16u);
                    unsigned k2 = (__float_as_uint(acc[mi][2][reg]) & 0xFFFFFE00u) | (brb | 32u);
                    unsigned k3 = (__float_as_uint(acc[mi][3][reg]) & 0xFFFFFE00u) | (brb | 48u);
                    float f0 = __uint_as_float(k0), f1 = __uint_as_float(k1);
                    float f2 = __uint_as_float(k2), f3 = __uint_as_float(k3);
                    float h01 = fmaxf(f0, f1), l01 = fminf(f0, f1);
                    float h23 = fmaxf(f2, f3), l23 = fminf(f2, f3);
                    float hi = fmaxf(h01, h23);
                    float lo = fmaxf(fminf(h01, h23), fmaxf(l01, l23));
                    int colL = mi * 16 + lhi * 4 + reg;
                    cbw[w][colL * 17 + l15] = make_float2(hi, lo);
                }
            }
        }

        // ---- ROW top-2 (22-bit key | c*32 + col-local), mi-split chains ----
        {
            const int cS = c << 5;
#pragma unroll
            for (int mi = 0; mi < 2; ++mi) {
#pragma unroll
                for (int reg = 0; reg < 4; ++reg) {
                    const int ib = (lhi * 4 + mi * 16 + reg) | cS;
#pragma unroll
                    for (int ni = 0; ni < 4; ++ni) {
                        int kb = (__float_as_int(acc[mi][ni][reg]) & (int)ROWKEY_MASK) | ib;
                        float fk = __int_as_float(kb);
                        float h = fmaxf(tv0[mi][ni], fk);
                        float lo2 = fminf(tv0[mi][ni], fk);
                        tv0[mi][ni] = h;
                        tv1[mi][ni] = fmaxf(tv1[mi][ni], lo2);
                    }
                }
            }
        }

        // ---- wave merge (no barrier: same-wave DS ops are in-order):
        //      2 lanes/col read 8 pairs each -> top-2 of 16 -> colwave ----
        {
            int colR = l >> 1, half = l & 1;
            const float2* src = &cbw[w][colR * 17 + half * 8];
            float a = NEG_INF_F, b = NEG_INF_F;
#pragma unroll
            for (int j = 0; j < 8; ++j) {
                float2 v = src[j];
                float t0 = fmaxf(a, v.x);
                float t1 = fmaxf(fminf(a, v.x), fmaxf(b, v.y));
                a = t0; b = t1;
            }
            colwave[c & 1][colR][w * 2 + half] = make_float2(a, b);
        }
    }
    __syncthreads();       // publishes colwave[(NCHUNK-1)&1]; cbw free
    MERGE2(NCHUNK - 1);
#undef STAGE
#undef MERGE2

    // ---- final row merge: 16 keys per row -> top-3 keys per split ----
    int4* mrg = (int4*)cbw;        // [512 rows][4 lhi] int4 = 32 KB (cbw is 34)
#pragma unroll
    for (int ni = 0; ni < 4; ++ni) {
        int rloc = w * 64 + ni * 16 + l15;
        int4 p;
        p.x = __float_as_int(tv0[0][ni]);
        p.y = __float_as_int(tv1[0][ni]);
        p.z = __float_as_int(tv0[1][ni]);
        p.w = __float_as_int(tv1[1][ni]);
        mrg[rloc * 4 + lhi] = p;
    }
    __syncthreads();
    {
        float b0 = NEG_INF_F, b1 = NEG_INF_F, b2 = NEG_INF_F;
#pragma unroll
        for (int q = 0; q < 4; ++q) {
            int4 p = mrg[t * 4 + q];
            int ks[4] = {p.x, p.y, p.z, p.w};
#pragma unroll
            for (int j = 0; j < 4; ++j) {
                float k = __int_as_float(ks[j]), h;
                h = fmaxf(b0, k); k = fminf(b0, k); b0 = h;
                h = fmaxf(b1, k); k = fminf(b1, k); b1 = h;
                b2 = fmaxf(b2, k);
            }
        }
        int rowG = rowBase + t;
        unsigned* o = cand_row + (size_t)rowG * RKEYS + split * 3;
        o[0] = __float_as_uint(b0);
        o[1] = __float_as_uint(b1);
        o[2] = __float_as_uint(b2);
    }
}

// ------------------------------------------------------------------
// mergecol: per column, key top-6 of 96 block partials -> rows
// ------------------------------------------------------------------
__global__ __launch_bounds__(256) void mergecol_kernel(
    const unsigned* __restrict__ cand_col, int* __restrict__ col6)
{
    int col = blockIdx.x * 256 + threadIdx.x;   // 0..16383
    float bv0 = NEG_INF_F, bv1 = NEG_INF_F, bv2 = NEG_INF_F;
    float bv3 = NEG_INF_F, bv4 = NEG_INF_F, bv5 = NEG_INF_F;
    for (int s = 0; s < NCOLSLOT; ++s) {
        float k = __uint_as_float(cand_col[(size_t)s * NP + col]);
        float h;
        h = fmaxf(bv0, k); k = fminf(bv0, k); bv0 = h;
        h = fmaxf(bv1, k); k = fminf(bv1, k); bv1 = h;
        h = fmaxf(bv2, k); k = fminf(bv2, k); bv2 = h;
        h = fmaxf(bv3, k); k = fminf(bv3, k); bv3 = h;
        h = fmaxf(bv4, k); k = fminf(bv4, k); bv4 = h;
        bv5 = fmaxf(bv5, k);
    }
    const float thr = bv5;
    int r0 = 0, r1 = 0, r2 = 0, r3 = 0, r4 = 0, r5 = 0;
    int cnt = 0;
    for (int s = 0; s < NCOLSLOT; ++s) {
        unsigned ku = cand_col[(size_t)s * NP + col];
        float k = __uint_as_float(ku);
        bool take = (k >= thr) && (cnt < 6);
        int row = (s / 3) * ROWS + (int)(ku & 0x1FFu);
        r0 = (take && cnt == 0) ? row : r0;
        r1 = (take && cnt == 1) ? row : r1;
        r2 = (take && cnt == 2) ? row : r2;
        r3 = (take && cnt == 3) ? row : r3;
        r4 = (take && cnt == 4) ? row : r4;
        r5 = (take && cnt == 5) ? row : r5;
        cnt += take ? 1 : 0;
    }
    int* o = col6 + (size_t)col * 6;
    o[0] = r0; o[1] = r1; o[2] = r2; o[3] = r3; o[4] = r4; o[5] = r5;
}

// ------------------------------------------------------------------
// rescore_row: key-threshold top-8 of 48, then exact fp32 top-2
// (wave per row; branch is wave-uniform)
// ------------------------------------------------------------------
__global__ __launch_bounds__(256) void rescore_row_kernel(
    const float* __restrict__ AT, const float* __restrict__ BT,
    const unsigned* __restrict__ cand_row, float4* __restrict__ final12)
{
    const int t = threadIdx.x;
    const int w = t >> 6, l = t & 63;
    const int row = blockIdx.x * 4 + w;    // 0..16383
    float4 rv = *(const float4*)(AT + ((size_t)row << 8) + l * 4);
    const unsigned* __restrict__ cl = cand_row + (size_t)row * RKEYS;

    // 8th-largest key (all lanes compute identically from broadcast loads)
    float t8[8];
#pragma unroll
    for (int q = 0; q < 8; ++q) t8[q] = NEG_INF_F;
#pragma unroll 4
    for (int s = 0; s < RKEYS; ++s) {
        float k = __uint_as_float(cl[s]);
#pragma unroll
        for (int q = 0; q < 8; ++q) {
            float h = fmaxf(t8[q], k);
            k = fminf(t8[q], k);
            t8[q] = h;
        }
    }
    const float thr = t8[7];

    float v0 = -4.f, v1 = -4.f; int i0 = 0x7fffffff, i1 = 0x7fffffff;
    int taken = 0;
    for (int s = 0; s < RKEYS; ++s) {
        unsigned ku = cl[s];
        float kf = __uint_as_float(ku);
        if (kf >= thr && taken < 8) {      // wave-uniform
            ++taken;
            int idx = (s / 3) * CPS + (int)(ku & 0x3FFu);
            float4 cv = *(const float4*)(BT + ((size_t)idx << 8) + l * 4);
            float d = rv.x * cv.x;
            d = fmaf(rv.y, cv.y, d);
            d = fmaf(rv.z, cv.z, d);
            d = fmaf(rv.w, cv.w, d);
#pragma unroll
            for (int m = 1; m < 64; m <<= 1) d += __shfl_xor(d, m, 64);
            if (d > v0 || (d == v0 && idx < i0)) {
                v1 = v0; i1 = i0; v0 = d; i0 = idx;
            } else if (d > v1 || (d == v1 && idx < i1)) {
                v1 = d; i1 = idx;
            }
        }
    }
    if (l == 0) {
        float4 r; r.x = v0; r.y = v1;
        r.z = __int_as_float(i0); r.w = __int_as_float(i1);
        final12[row] = r;
    }
}

// ------------------------------------------------------------------
// rescore_col: exact fp32 top-2 over 6 cands per column (wave per col)
// ------------------------------------------------------------------
__global__ __launch_bounds__(256) void rescore_col_kernel(
    const float* __restrict__ AT, const float* __restrict__ BT,
    const int* __restrict__ col6,
    int* __restrict__ nn21, float* __restrict__ ratio21)
{
    const int t = threadIdx.x;
    const int w = t >> 6, l = t & 63;
    const int col = blockIdx.x * 4 + w;    // 0..16383
    float4 rv = *(const float4*)(BT + ((size_t)col << 8) + l * 4);
    float v0 = -4.f, v1 = -4.f; int i0 = 0x7fffffff, i1 = 0x7fffffff;
    const int* __restrict__ cl = col6 + (size_t)col * 6;
#pragma unroll
    for (int j = 0; j < 6; ++j) {
        int idx = cl[j];
        float4 cv = *(const float4*)(AT + ((size_t)idx << 8) + l * 4);
        float d = rv.x * cv.x;
        d = fmaf(rv.y, cv.y, d);
        d = fmaf(rv.z, cv.z, d);
        d = fmaf(rv.w, cv.w, d);
#pragma unroll
        for (int m = 1; m < 64; m <<= 1) d += __shfl_xor(d, m, 64);
        if (d > v0 || (d == v0 && idx < i0)) {
            v1 = v0; i1 = i0; v0 = d; i0 = idx;
        } else if (d > v1 || (d == v1 && idx < i1)) {
            v1 = d; i1 = idx;
        }
    }
    if (l == 0) {
        nn21[col] = i0;
        float d0 = sqrtf(fmaxf(2.f - 2.f * v0, 1e-12f));
        float d1 = sqrtf(fmaxf(2.f - 2.f * v1, 1e-12f));
        ratio21[col] = d0 / (d1 + EPSF);
    }
}

// ------------------------------------------------------------------
// final: mutual check, ratio test, border mask
// ------------------------------------------------------------------
__global__ void final_kernel(const float4* __restrict__ final12,
                             const int* __restrict__ nn21,
                             const float* __restrict__ ratio21,
                             float* __restrict__ out) {
    int i = blockIdx.x * blockDim.x + threadIdx.x;  // 0..16383
    float4 a = final12[i];
    float d0 = sqrtf(fmaxf(2.f - 2.f * a.x, 1e-12f));
    float d1 = sqrtf(fmaxf(2.f - 2.f * a.y, 1e-12f));
    int nn = __float_as_int(a.z);
    float r12 = d0 / (d1 + EPSF);
    bool mutual = (nn21[nn] == i);
    float r = fmaxf(r12, ratio21[nn]);
    int xA = i & (WDIM - 1), yA = i >> 7;
    int xB = nn & (WDIM - 1), yB = nn >> 7;
    bool border = (xA == 0) || (xA == WDIM - 1) || (yA == 0) || (yA == WDIM - 1) ||
                  (xB == 0) || (xB == WDIM - 1) || (yB == 0) || (yB == WDIM - 1);
    bool valid = mutual && (r < 0.95f) && !border;
    out[2 * i]       = valid ? d0 : 0.f;
    out[2 * i + 1]   = valid ? d1 : 0.f;
    out[2 * NP + i]  = (float)nn;
    out[3 * NP + i]  = valid ? 1.f : 0.f;
}

extern "C" void kernel_launch(void* const* d_in, const int* in_sizes, int n_in,
                              void* d_out, int out_size, void* d_ws, size_t ws_size,
                              hipStream_t stream) {
    (void)in_sizes; (void)n_in; (void)out_size; (void)ws_size;
    const float* A = (const float*)d_in[0];
    const float* B = (const float*)d_in[1];
    float* out = (float*)d_out;

    char* ws = (char*)d_ws;
    float* AT = (float*)ws;                                          // 16 MB
    float* BT = AT + (size_t)NP * CH;                                // 16 MB
    unsigned short* Abf = (unsigned short*)(BT + (size_t)NP * CH);   // 8 MB
    unsigned short* Bbf = Abf + (size_t)NP * CH;                     // 8 MB
    unsigned* cand_row = (unsigned*)(Bbf + (size_t)NP * CH);         // 3 MB
    unsigned* cand_col = cand_row + (size_t)NP * RKEYS;              // 6.3 MB
    int* col6 = (int*)(cand_col + (size_t)NCOLSLOT * NP);            // 0.4 MB
    float4* final12 = (float4*)(col6 + (size_t)NP * 6);              // 256 KB
    int* nn21 = (int*)(final12 + NP);                                // 64 KB
    float* ratio21 = (float*)(nn21 + NP);                            // 64 KB

    prep_kernel<<<512, 256, 0, stream>>>(A, B, AT, BT, Abf, Bbf);
    simk_kernel<<<NRT * SPLITS, 512, 0, stream>>>(Abf, Bbf, cand_row, cand_col);
    mergecol_kernel<<<NP / 256, 256, 0, stream>>>(cand_col, col6);
    rescore_row_kernel<<<NP / 4, 256, 0, stream>>>(AT, BT, cand_row, final12);
    rescore_col_kernel<<<NP / 4, 256, 0, stream>>>(AT, BT, col6, nn21, ratio21);
    final_kernel<<<NP / 256, 256, 0, stream>>>(final12, nn21, ratio21, out);
}

// Round 18
// 250.832 us; speedup vs baseline: 2.2683x; 1.1535x over previous
//
#include <hip/hip_runtime.h>
#include <math.h>

#define NP 16384      // pixels per map (128*128)
#define CH 256        // channels (K)
#define WDIM 128
#define EPSF 1e-8f

#define CHUNK 32
#define SPLITS 8
#define CPS (NP / SPLITS)            // 2048 cols per split
#define NCHUNK (CPS / CHUNK)         // 64
#define ROWS 512                     // rows per block (8 waves x 64)
#define NRT (NP / ROWS)              // 32 row tiles
#define CHUNK_BYTES (CHUNK * CH * 2) // 16384
#define NCOLSLOT (NRT * 3)           // 96 col-candidate slots per column

typedef short short8 __attribute__((ext_vector_type(8)));
typedef float floatx4 __attribute__((ext_vector_type(4)));

typedef __attribute__((address_space(1))) const unsigned int gu32;
typedef __attribute__((address_space(3))) unsigned int lu32;

#define NEG_INF_F __int_as_float(0xFF800000)
#define ROWKEY_MASK 0xFFFFF800u      // 21-bit sim | 11-bit local col

// ------------------------------------------------------------------
// prep: per-pixel 1/||d||, fp32 normalized transposed [pix][256],
// bf16 normalized swizzled (element ch stored at ch ^ ((pix&7)<<3))
// ------------------------------------------------------------------
__global__ __launch_bounds__(256) void prep_kernel(
    const float* __restrict__ A, const float* __restrict__ B,
    float* __restrict__ AT, float* __restrict__ BT,
    unsigned short* __restrict__ Abf, unsigned short* __restrict__ Bbf)
{
    __shared__ float tile[64 * 257];
    __shared__ float rnv[64];
    const int bid = blockIdx.x;
    const float* __restrict__ src = (bid < 256) ? A : B;
    float* __restrict__ dstT = (bid < 256) ? AT : BT;
    unsigned short* __restrict__ dstb = (bid < 256) ? Abf : Bbf;
    const int pixBase = (bid & 255) * 64;
    const int t = threadIdx.x;

    for (int k = 0; k < 64 * 256; k += 256) {
        int idx = k + t;
        int p = idx & 63;
        int c = idx >> 6;
        tile[p * 257 + c] = src[(size_t)c * NP + pixBase + p];
    }
    __syncthreads();
    if (t < 64) {
        float s = 0.f;
        for (int c = 0; c < 256; ++c) { float v = tile[t * 257 + c]; s = fmaf(v, v, s); }
        rnv[t] = 1.0f / sqrtf(s);
    }
    __syncthreads();
    for (int k = 0; k < 64 * 256; k += 256) {
        int idx = k + t;
        int p = idx >> 8;
        int c = idx & 255;
        dstT[((size_t)(pixBase + p) << 8) + c] = tile[p * 257 + c] * rnv[p];
    }
    for (int k = 0; k < 64 * 128; k += 256) {
        int idx = k + t;
        int p = idx >> 7;
        int c2 = (idx & 127) * 2;
        float rn = rnv[p];
        float v0 = tile[p * 257 + c2] * rn;
        float v1 = tile[p * 257 + c2 + 1] * rn;
        unsigned u0 = __float_as_uint(v0); u0 = (u0 + 0x7fffu + ((u0 >> 16) & 1u)) >> 16;
        unsigned u1 = __float_as_uint(v1); u1 = (u1 + 0x7fffu + ((u1 >> 16) & 1u)) >> 16;
        unsigned sw = ((unsigned)(p & 7)) << 3;
        int e = ((pixBase + p) << 8) + (c2 ^ (int)sw);
        *(unsigned*)(dstb + e) = (u0 & 0xffffu) | (u1 << 16);
    }
}

// ------------------------------------------------------------------
// simk ONE-PASS, 512-row blocks (8 waves x 64 rows/wave), SPLITS=8,
// 1 barrier/chunk — EXACT R15 configuration (proven 203 us, absmax 0).
// Col path per chunk: per-lane sorted pair -> wave-private cbw[w]
// (same-wave DS in-order, no barrier) -> 2 lanes/col top-2 of 16
// -> colwave dbuf (16 partials/col) -> deferred MERGE2 (t<32):
// block top-3/col -> cand_col. Rows (A) = B-operand in regs (pinned).
// ------------------------------------------------------------------
__global__ __launch_bounds__(512, 2) void simk_kernel(
    const unsigned short* __restrict__ Abf, const unsigned short* __restrict__ Bbf,
    unsigned* __restrict__ cand_row, unsigned* __restrict__ cand_col)
{
    __shared__ __align__(16) char smem[2 * CHUNK_BYTES];      // 32 KB staging
    __shared__ __align__(16) float2 cbw[8][32 * 17 + 4];      // 35 KB wave-private
    __shared__ __align__(16) float2 colwave[2][32][17];       // 8.7 KB dbuf
    const int bid = blockIdx.x;
    const int rt = bid >> 3;          // 0..31
    const int split = bid & 7;
    const int t = threadIdx.x;        // 0..511
    const int w = t >> 6;             // 0..7
    const int l = t & 63;
    const int l15 = l & 15, lhi = l >> 4;
    const int rowBase = rt * ROWS;
    const int colBase = split * CPS;

    // --- row-descriptor fragments (B-operand) from A, pinned ---
    short8 Bfr[4][8];
#pragma unroll
    for (int ni = 0; ni < 4; ++ni) {
        int pix = rowBase + w * 64 + ni * 16 + l15;
        const unsigned short* pr = Abf + ((size_t)pix << 8);
        int sw = (pix & 7) << 3;
#pragma unroll
        for (int kk = 0; kk < 8; ++kk) {
            int ke = kk * 32 + lhi * 8;
            Bfr[ni][kk] = *(const short8*)(pr + (ke ^ sw));
        }
    }
#pragma unroll
    for (int ni = 0; ni < 4; ++ni)
#pragma unroll
        for (int kk = 0; kk < 8; ++kk)
            asm volatile("" : "+v"(Bfr[ni][kk]));

    // --- LDS byte offsets for A-operand frags (mi=0; mi=1 is +8192) ---
    int aoff[8];
    {
        int cp = l15;
        int sw = (cp & 7) << 3;
#pragma unroll
        for (int kk = 0; kk < 8; ++kk) {
            int ke = kk * 32 + lhi * 8;
            aoff[kk] = (cp * 256 + (ke ^ sw)) * 2;
        }
    }

    // row running top-2 per (mi, ni) stream — split by mi for ILP
    float tv0[2][4], tv1[2][4];
#pragma unroll
    for (int mi = 0; mi < 2; ++mi)
#pragma unroll
        for (int ni = 0; ni < 4; ++ni) { tv0[mi][ni] = NEG_INF_F; tv1[mi][ni] = NEG_INF_F; }

    const char* gbase = (const char*)(Bbf + ((size_t)colBase << 8));
    const floatx4 fzero = {0.f, 0.f, 0.f, 0.f};
    floatx4 acc[2][4];

#define STAGE(CIDX, BUFSEL) do {                                              \
        const char* gsrc_ = gbase + (size_t)(CIDX) * CHUNK_BYTES;             \
        char* bdst_ = smem + (BUFSEL) * CHUNK_BYTES;                          \
        _Pragma("unroll")                                                     \
        for (int r_ = 0; r_ < 2; ++r_) {                                      \
            int off_ = w * 2048 + r_ * 1024;                                  \
            __builtin_amdgcn_global_load_lds((gu32*)(gsrc_ + off_ + l * 16),  \
                                             (lu32*)(bdst_ + off_), 16, 0, 0);\
        }                                                                     \
    } while (0)

#define MERGE2(CIDX) do {                                                     \
        if (t < 32) {                                                         \
            float b0_ = NEG_INF_F, b1_ = NEG_INF_F, b2_ = NEG_INF_F;          \
            _Pragma("unroll")                                                 \
            for (int j_ = 0; j_ < 16; ++j_) {                                 \
                float2 v_ = colwave[(CIDX) & 1][t][j_];                       \
                float k_ = v_.x, h_;                                          \
                h_ = fmaxf(b0_, k_); k_ = fminf(b0_, k_); b0_ = h_;           \
                h_ = fmaxf(b1_, k_); k_ = fminf(b1_, k_); b1_ = h_;           \
                b2_ = fmaxf(b2_, k_);                                         \
                k_ = v_.y;                                                    \
                h_ = fmaxf(b0_, k_); k_ = fminf(b0_, k_); b0_ = h_;           \
                h_ = fmaxf(b1_, k_); k_ = fminf(b1_, k_); b1_ = h_;           \
                b2_ = fmaxf(b2_, k_);                                         \
            }                                                                 \
            int colG_ = colBase + (CIDX) * 32 + t;                            \
            cand_col[(size_t)(rt * 3 + 0) * NP + colG_] = __float_as_uint(b0_);\
            cand_col[(size_t)(rt * 3 + 1) * NP + colG_] = __float_as_uint(b1_);\
            cand_col[(size_t)(rt * 3 + 2) * NP + colG_] = __float_as_uint(b2_);\
        }                                                                     \
    } while (0)

    STAGE(0, 0);

    for (int c = 0; c < NCHUNK; ++c) {
        __syncthreads();   // B1: staging(c) ready; colwave[(c-1)&1] published
        if (c + 1 < NCHUNK) STAGE(c + 1, (c + 1) & 1);
        if (c > 0) MERGE2(c - 1);

        // ---- COMPUTE: 64 MFMA into acc ----
        {
            const char* buf = smem + (c & 1) * CHUNK_BYTES;
            __builtin_amdgcn_s_setprio(1);
            {
                short8 a0 = *(const short8*)(buf + aoff[0]);
                short8 a1 = *(const short8*)(buf + aoff[0] + 8192);
#pragma unroll
                for (int ni = 0; ni < 4; ++ni) {
                    acc[0][ni] = __builtin_amdgcn_mfma_f32_16x16x32_bf16(a0, Bfr[ni][0], fzero, 0, 0, 0);
                    acc[1][ni] = __builtin_amdgcn_mfma_f32_16x16x32_bf16(a1, Bfr[ni][0], fzero, 0, 0, 0);
                }
            }
#pragma unroll
            for (int kk = 1; kk < 8; ++kk) {
                short8 a0 = *(const short8*)(buf + aoff[kk]);
                short8 a1 = *(const short8*)(buf + aoff[kk] + 8192);
#pragma unroll
                for (int ni = 0; ni < 4; ++ni) {
                    acc[0][ni] = __builtin_amdgcn_mfma_f32_16x16x32_bf16(a0, Bfr[ni][kk], acc[0][ni], 0, 0, 0);
                    acc[1][ni] = __builtin_amdgcn_mfma_f32_16x16x32_bf16(a1, Bfr[ni][kk], acc[1][ni], 0, 0, 0);
                }
            }
            __builtin_amdgcn_s_setprio(0);
        }

        // ---- COL extract: per-lane sorted pair of 4 rows -> cbw[w] ----
        {
            const unsigned brb = ((unsigned)w << 6) | (unsigned)l15;
#pragma unroll
            for (int mi = 0; mi < 2; ++mi) {
#pragma unroll
                for (int reg = 0; reg < 4; ++reg) {
                    unsigned k0 = (__float_as_uint(acc[mi][0][reg]) & 0xFFFFFE00u) | brb;
                    unsigned k1 = (__float_as_uint(acc[mi][1][reg]) & 0xFFFFFE00u) | (brb | 16u);
                    unsigned k2 = (__float_as_uint(acc[mi][2][reg]) & 0xFFFFFE00u) | (brb | 32u);
                    unsigned k3 = (__float_as_uint(acc[mi][3][reg]) & 0xFFFFFE00u) | (brb | 48u);
                    float f0 = __uint_as_float(k0), f1 = __uint_as_float(k1);
                    float f2 = __uint_as_float(k2), f3 = __uint_as_float(k3);
                    float h01 = fmaxf(f0, f1), l01 = fminf(f0, f1);
                    float h23 = fmaxf(f2, f3), l23 = fminf(f2, f3);
                    float hi = fmaxf(h01, h23);
                    float lo = fmaxf(fminf(h01, h23), fmaxf(l01, l23));
                    int colL = mi * 16 + lhi * 4 + reg;
                    cbw[w][colL * 17 + l15] = make_float2(hi, lo);
                }
            }
        }

        // ---- ROW top-2 (21-bit key | c*32 + col-local), mi-split chains ----
        {
            const int cS = c << 5;
#pragma unroll
            for (int mi = 0; mi < 2; ++mi) {
#pragma unroll
                for (int reg = 0; reg < 4; ++reg) {
                    const int ib = (lhi * 4 + mi * 16 + reg) | cS;
#pragma unroll
                    for (int ni = 0; ni < 4; ++ni) {
                        int kb = (__float_as_int(acc[mi][ni][reg]) & (int)ROWKEY_MASK) | ib;
                        float fk = __int_as_float(kb);
                        float h = fmaxf(tv0[mi][ni], fk);
                        float lo2 = fminf(tv0[mi][ni], fk);
                        tv0[mi][ni] = h;
                        tv1[mi][ni] = fmaxf(tv1[mi][ni], lo2);
                    }
                }
            }
        }

        // ---- wave merge (no barrier: same-wave DS ops are in-order):
        //      2 lanes/col read 8 pairs each -> top-2 of 16 -> colwave ----
        {
            int colR = l >> 1, half = l & 1;
            const float2* src = &cbw[w][colR * 17 + half * 8];
            float a = NEG_INF_F, b = NEG_INF_F;
#pragma unroll
            for (int j = 0; j < 8; ++j) {
                float2 v = src[j];
                float t0 = fmaxf(a, v.x);
                float t1 = fmaxf(fminf(a, v.x), fmaxf(b, v.y));
                a = t0; b = t1;
            }
            colwave[c & 1][colR][w * 2 + half] = make_float2(a, b);
        }
    }
    __syncthreads();       // publishes colwave[(NCHUNK-1)&1]; cbw free
    MERGE2(NCHUNK - 1);
#undef STAGE
#undef MERGE2

    // ---- final row merge: 16 keys per row -> top-3 keys per split ----
    int4* mrg = (int4*)cbw;        // [512 rows][4 lhi] int4 = 32 KB (cbw is 35)
#pragma unroll
    for (int ni = 0; ni < 4; ++ni) {
        int rloc = w * 64 + ni * 16 + l15;
        int4 p;
        p.x = __float_as_int(tv0[0][ni]);
        p.y = __float_as_int(tv1[0][ni]);
        p.z = __float_as_int(tv0[1][ni]);
        p.w = __float_as_int(tv1[1][ni]);
        mrg[rloc * 4 + lhi] = p;
    }
    __syncthreads();
    {
        float b0 = NEG_INF_F, b1 = NEG_INF_F, b2 = NEG_INF_F;
#pragma unroll
        for (int q = 0; q < 4; ++q) {
            int4 p = mrg[t * 4 + q];
            int ks[4] = {p.x, p.y, p.z, p.w};
#pragma unroll
            for (int j = 0; j < 4; ++j) {
                float k = __int_as_float(ks[j]), h;
                h = fmaxf(b0, k); k = fminf(b0, k); b0 = h;
                h = fmaxf(b1, k); k = fminf(b1, k); b1 = h;
                b2 = fmaxf(b2, k);
            }
        }
        int rowG = rowBase + t;
        unsigned* o = cand_row + (size_t)rowG * 24 + split * 3;
        o[0] = __float_as_uint(b0);
        o[1] = __float_as_uint(b1);
        o[2] = __float_as_uint(b2);
    }
}

// ------------------------------------------------------------------
// mergecol PARALLEL: 4 threads/col over disjoint 24-slot subsets,
// each keeps top-6 (key,row) pairs (union contains overall top-6);
// one thread merges 24 pairs -> col6. 64 cols/block, 256 blocks
// (old version: 64 blocks, 96-long serial chains -> latency-bound).
// ------------------------------------------------------------------
__global__ __launch_bounds__(256) void mergecol_kernel(
    const unsigned* __restrict__ cand_col, int* __restrict__ col6)
{
    __shared__ int2 pairs[64][4][6];   // 12 KB
    const int t = threadIdx.x;
    const int colL = t >> 2, g = t & 3;
    const int col = blockIdx.x * 64 + colL;

    float bk[6]; int br[6];
#pragma unroll
    for (int q = 0; q < 6; ++q) { bk[q] = NEG_INF_F; br[q] = 0; }
#pragma unroll 4
    for (int k = 0; k < NCOLSLOT / 4; ++k) {
        int s = g + (k << 2);
        unsigned ku = cand_col[(size_t)s * NP + col];
        float key = __uint_as_float(ku);
        int row = (s / 3) * ROWS + (int)(ku & 0x1FFu);
#pragma unroll
        for (int q = 0; q < 6; ++q) {
            bool gt = key > bk[q];
            float ek = gt ? bk[q] : key;
            int   er = gt ? br[q] : row;
            bk[q] = gt ? key : bk[q];
            br[q] = gt ? row : br[q];
            key = ek; row = er;
        }
    }
#pragma unroll
    for (int q = 0; q < 6; ++q)
        pairs[colL][g][q] = make_int2(__float_as_int(bk[q]), br[q]);
    __syncthreads();

    if (g == 0) {
        float mk[6]; int mr[6];
#pragma unroll
        for (int q = 0; q < 6; ++q) { mk[q] = NEG_INF_F; mr[q] = 0; }
#pragma unroll
        for (int j = 0; j < 24; ++j) {
            int2 p = pairs[colL][j >> 2][0];   // placeholder; replaced below
            (void)p;
        }
        // merge 4 groups x 6 sorted pairs
#pragma unroll
        for (int gg = 0; gg < 4; ++gg) {
#pragma unroll
            for (int q2 = 0; q2 < 6; ++q2) {
                int2 p = pairs[colL][gg][q2];
                float key = __int_as_float(p.x);
                int row = p.y;
#pragma unroll
                for (int q = 0; q < 6; ++q) {
                    bool gt = key > mk[q];
                    float ek = gt ? mk[q] : key;
                    int   er = gt ? mr[q] : row;
                    mk[q] = gt ? key : mk[q];
                    mr[q] = gt ? row : mr[q];
                    key = ek; row = er;
                }
            }
        }
        int* o = col6 + (size_t)col * 6;
#pragma unroll
        for (int q = 0; q < 6; ++q) o[q] = mr[q];
    }
}

// ------------------------------------------------------------------
// rescore (FUSED): pass 0 = row rescore (threshold top-8 of 24 keys,
// exact fp32 top-2); pass 1 = col rescore (6 cands). Wave per job.
// ------------------------------------------------------------------
__global__ __launch_bounds__(256) void rescore_kernel(
    const float* __restrict__ AT, const float* __restrict__ BT,
    const unsigned* __restrict__ cand_row, const int* __restrict__ col6,
    float4* __restrict__ final12,
    int* __restrict__ nn21, float* __restrict__ ratio21)
{
    const int t = threadIdx.x;
    const int w = t >> 6, l = t & 63;
    const int gjob = blockIdx.x * 4 + w;   // 0..32767
    const int pass = gjob >> 14;
    const int id = gjob & (NP - 1);

    if (pass == 0) {
        const int row = id;
        float4 rv = *(const float4*)(AT + ((size_t)row << 8) + l * 4);
        const unsigned* __restrict__ cl = cand_row + (size_t)row * 24;

        float t8[8];
#pragma unroll
        for (int q = 0; q < 8; ++q) t8[q] = NEG_INF_F;
#pragma unroll
        for (int s = 0; s < 24; ++s) {
            float k = __uint_as_float(cl[s]);
#pragma unroll
            for (int q = 0; q < 8; ++q) {
                float h = fmaxf(t8[q], k);
                k = fminf(t8[q], k);
                t8[q] = h;
            }
        }
        const float thr = t8[7];

        float v0 = -4.f, v1 = -4.f; int i0 = 0x7fffffff, i1 = 0x7fffffff;
        int taken = 0;
        for (int s = 0; s < 24; ++s) {
            unsigned ku = cl[s];
            float kf = __uint_as_float(ku);
            if (kf >= thr && taken < 8) {      // wave-uniform
                ++taken;
                int idx = (s / 3) * CPS + (int)(ku & 0x7FFu);
                float4 cv = *(const float4*)(BT + ((size_t)idx << 8) + l * 4);
                float d = rv.x * cv.x;
                d = fmaf(rv.y, cv.y, d);
                d = fmaf(rv.z, cv.z, d);
                d = fmaf(rv.w, cv.w, d);
#pragma unroll
                for (int m = 1; m < 64; m <<= 1) d += __shfl_xor(d, m, 64);
                if (d > v0 || (d == v0 && idx < i0)) {
                    v1 = v0; i1 = i0; v0 = d; i0 = idx;
                } else if (d > v1 || (d == v1 && idx < i1)) {
                    v1 = d; i1 = idx;
                }
            }
        }
        if (l == 0) {
            float4 r; r.x = v0; r.y = v1;
            r.z = __int_as_float(i0); r.w = __int_as_float(i1);
            final12[row] = r;
        }
    } else {
        const int col = id;
        float4 rv = *(const float4*)(BT + ((size_t)col << 8) + l * 4);
        float v0 = -4.f, v1 = -4.f; int i0 = 0x7fffffff, i1 = 0x7fffffff;
        const int* __restrict__ cl = col6 + (size_t)col * 6;
#pragma unroll
        for (int j = 0; j < 6; ++j) {
            int idx = cl[j];
            float4 cv = *(const float4*)(AT + ((size_t)idx << 8) + l * 4);
            float d = rv.x * cv.x;
            d = fmaf(rv.y, cv.y, d);
            d = fmaf(rv.z, cv.z, d);
            d = fmaf(rv.w, cv.w, d);
#pragma unroll
            for (int m = 1; m < 64; m <<= 1) d += __shfl_xor(d, m, 64);
            if (d > v0 || (d == v0 && idx < i0)) {
                v1 = v0; i1 = i0; v0 = d; i0 = idx;
            } else if (d > v1 || (d == v1 && idx < i1)) {
                v1 = d; i1 = idx;
            }
        }
        if (l == 0) {
            nn21[col] = i0;
            float d0 = sqrtf(fmaxf(2.f - 2.f * v0, 1e-12f));
            float d1 = sqrtf(fmaxf(2.f - 2.f * v1, 1e-12f));
            ratio21[col] = d0 / (d1 + EPSF);
        }
    }
}

// ------------------------------------------------------------------
// final: mutual check, ratio test, border mask
// ------------------------------------------------------------------
__global__ void final_kernel(const float4* __restrict__ final12,
                             const int* __restrict__ nn21,
                             const float* __restrict__ ratio21,
                             float* __restrict__ out) {
    int i = blockIdx.x * blockDim.x + threadIdx.x;  // 0..16383
    float4 a = final12[i];
    float d0 = sqrtf(fmaxf(2.f - 2.f * a.x, 1e-12f));
    float d1 = sqrtf(fmaxf(2.f - 2.f * a.y, 1e-12f));
    int nn = __float_as_int(a.z);
    float r12 = d0 / (d1 + EPSF);
    bool mutual = (nn21[nn] == i);
    float r = fmaxf(r12, ratio21[nn]);
    int xA = i & (WDIM - 1), yA = i >> 7;
    int xB = nn & (WDIM - 1), yB = nn >> 7;
    bool border = (xA == 0) || (xA == WDIM - 1) || (yA == 0) || (yA == WDIM - 1) ||
                  (xB == 0) || (xB == WDIM - 1) || (yB == 0) || (yB == WDIM - 1);
    bool valid = mutual && (r < 0.95f) && !border;
    out[2 * i]       = valid ? d0 : 0.f;
    out[2 * i + 1]   = valid ? d1 : 0.f;
    out[2 * NP + i]  = (float)nn;
    out[3 * NP + i]  = valid ? 1.f : 0.f;
}

extern "C" void kernel_launch(void* const* d_in, const int* in_sizes, int n_in,
                              void* d_out, int out_size, void* d_ws, size_t ws_size,
                              hipStream_t stream) {
    (void)in_sizes; (void)n_in; (void)out_size; (void)ws_size;
    const float* A = (const float*)d_in[0];
    const float* B = (const float*)d_in[1];
    float* out = (float*)d_out;

    char* ws = (char*)d_ws;
    float* AT = (float*)ws;                                          // 16 MB
    float* BT = AT + (size_t)NP * CH;                                // 16 MB
    unsigned short* Abf = (unsigned short*)(BT + (size_t)NP * CH);   // 8 MB
    unsigned short* Bbf = Abf + (size_t)NP * CH;                     // 8 MB
    unsigned* cand_row = (unsigned*)(Bbf + (size_t)NP * CH);         // 1.5 MB
    unsigned* cand_col = cand_row + (size_t)NP * 24;                 // 6.3 MB
    int* col6 = (int*)(cand_col + (size_t)NCOLSLOT * NP);            // 0.4 MB
    float4* final12 = (float4*)(col6 + (size_t)NP * 6);              // 256 KB
    int* nn21 = (int*)(final12 + NP);                                // 64 KB
    float* ratio21 = (float*)(nn21 + NP);                            // 64 KB

    prep_kernel<<<512, 256, 0, stream>>>(A, B, AT, BT, Abf, Bbf);
    simk_kernel<<<NRT * SPLITS, 512, 0, stream>>>(Abf, Bbf, cand_row, cand_col);
    mergecol_kernel<<<NP / 64, 256, 0, stream>>>(cand_col, col6);
    rescore_kernel<<<NP / 2, 256, 0, stream>>>(AT, BT, cand_row, col6,
                                               final12, nn21, ratio21);
    final_kernel<<<NP / 256, 256, 0, stream>>>(final12, nn21, ratio21, out);
}

// Round 19
// 243.066 us; speedup vs baseline: 2.3408x; 1.0319x over previous
//
#include <hip/hip_runtime.h>
#include <math.h>

#define NP 16384      // pixels per map (128*128)
#define CH 256        // channels (K)
#define WDIM 128
#define EPSF 1e-8f

#define CHUNK 64                     // cols per staged chunk (2 sub-batches of 32)
#define SPLITS 8
#define CPS (NP / SPLITS)            // 2048 cols per split
#define NCHUNK (CPS / CHUNK)         // 32
#define ROWS 512                     // rows per block (8 waves x 64)
#define NRT (NP / ROWS)              // 32 row tiles
#define CHUNK_BYTES (CHUNK * CH * 2) // 32768
#define NCOLSLOT (NRT * 3)           // 96 col-candidate slots per column

typedef short short8 __attribute__((ext_vector_type(8)));
typedef float floatx4 __attribute__((ext_vector_type(4)));

typedef __attribute__((address_space(1))) const unsigned int gu32;
typedef __attribute__((address_space(3))) unsigned int lu32;

#define NEG_INF_F __int_as_float(0xFF800000)
#define ROWKEY_MASK 0xFFFFF800u      // 21-bit sim | 11-bit local col

// ------------------------------------------------------------------
// prep: per-pixel 1/||d||, fp32 normalized transposed [pix][256],
// bf16 normalized swizzled (element ch stored at ch ^ ((pix&7)<<3))
// ------------------------------------------------------------------
__global__ __launch_bounds__(256) void prep_kernel(
    const float* __restrict__ A, const float* __restrict__ B,
    float* __restrict__ AT, float* __restrict__ BT,
    unsigned short* __restrict__ Abf, unsigned short* __restrict__ Bbf)
{
    __shared__ float tile[64 * 257];
    __shared__ float rnv[64];
    const int bid = blockIdx.x;
    const float* __restrict__ src = (bid < 256) ? A : B;
    float* __restrict__ dstT = (bid < 256) ? AT : BT;
    unsigned short* __restrict__ dstb = (bid < 256) ? Abf : Bbf;
    const int pixBase = (bid & 255) * 64;
    const int t = threadIdx.x;

    for (int k = 0; k < 64 * 256; k += 256) {
        int idx = k + t;
        int p = idx & 63;
        int c = idx >> 6;
        tile[p * 257 + c] = src[(size_t)c * NP + pixBase + p];
    }
    __syncthreads();
    if (t < 64) {
        float s = 0.f;
        for (int c = 0; c < 256; ++c) { float v = tile[t * 257 + c]; s = fmaf(v, v, s); }
        rnv[t] = 1.0f / sqrtf(s);
    }
    __syncthreads();
    for (int k = 0; k < 64 * 256; k += 256) {
        int idx = k + t;
        int p = idx >> 8;
        int c = idx & 255;
        dstT[((size_t)(pixBase + p) << 8) + c] = tile[p * 257 + c] * rnv[p];
    }
    for (int k = 0; k < 64 * 128; k += 256) {
        int idx = k + t;
        int p = idx >> 7;
        int c2 = (idx & 127) * 2;
        float rn = rnv[p];
        float v0 = tile[p * 257 + c2] * rn;
        float v1 = tile[p * 257 + c2 + 1] * rn;
        unsigned u0 = __float_as_uint(v0); u0 = (u0 + 0x7fffu + ((u0 >> 16) & 1u)) >> 16;
        unsigned u1 = __float_as_uint(v1); u1 = (u1 + 0x7fffu + ((u1 >> 16) & 1u)) >> 16;
        unsigned sw = ((unsigned)(p & 7)) << 3;
        int e = ((pixBase + p) << 8) + (c2 ^ (int)sw);
        *(unsigned*)(dstb + e) = (u0 & 0xffffu) | (u1 << 16);
    }
}

// ------------------------------------------------------------------
// simk ONE-PASS, 512-row blocks, CHUNK=64 (two 32-col sub-batches per
// staged chunk): barriers, STAGE issues, and MERGE2 instances per
// 2048 cols all HALVE vs R18 (the ~45% per-chunk stall — barrier
// convoy + vmcnt drain — amortizes over 2x work). Per sub-batch the
// pipeline is byte-identical to R18: 64 MFMA -> col extract (sorted
// pair -> wave-private cbw, same-wave DS in-order, no barrier) ->
// row top-2 -> wave merge (2 lanes/col, top-2 of 16) -> colwave dbuf.
// Deferred MERGE2 (t<64): block top-3/col of chunk c-1 -> cand_col.
// Rows (A) = B-operand in regs (pinned). cand_row = raw 21|11 keys.
// ------------------------------------------------------------------
__global__ __launch_bounds__(512, 2) void simk_kernel(
    const unsigned short* __restrict__ Abf, const unsigned short* __restrict__ Bbf,
    unsigned* __restrict__ cand_row, unsigned* __restrict__ cand_col)
{
    __shared__ __align__(16) char smem[2 * CHUNK_BYTES];      // 64 KB staging
    __shared__ __align__(16) float2 cbw[8][32 * 17 + 4];      // 35 KB wave-private
    __shared__ __align__(16) float2 colwave[2][64][17];       // 17.4 KB dbuf
    const int bid = blockIdx.x;
    const int rt = bid >> 3;          // 0..31
    const int split = bid & 7;
    const int t = threadIdx.x;        // 0..511
    const int w = t >> 6;             // 0..7
    const int l = t & 63;
    const int l15 = l & 15, lhi = l >> 4;
    const int rowBase = rt * ROWS;
    const int colBase = split * CPS;

    // --- row-descriptor fragments (B-operand) from A, pinned ---
    short8 Bfr[4][8];
#pragma unroll
    for (int ni = 0; ni < 4; ++ni) {
        int pix = rowBase + w * 64 + ni * 16 + l15;
        const unsigned short* pr = Abf + ((size_t)pix << 8);
        int sw = (pix & 7) << 3;
#pragma unroll
        for (int kk = 0; kk < 8; ++kk) {
            int ke = kk * 32 + lhi * 8;
            Bfr[ni][kk] = *(const short8*)(pr + (ke ^ sw));
        }
    }
#pragma unroll
    for (int ni = 0; ni < 4; ++ni)
#pragma unroll
        for (int kk = 0; kk < 8; ++kk)
            asm volatile("" : "+v"(Bfr[ni][kk]));

    // --- LDS byte offsets for A-operand frags (mi=0; mi=1 is +8192) ---
    int aoff[8];
    {
        int cp = l15;
        int sw = (cp & 7) << 3;
#pragma unroll
        for (int kk = 0; kk < 8; ++kk) {
            int ke = kk * 32 + lhi * 8;
            aoff[kk] = (cp * 256 + (ke ^ sw)) * 2;
        }
    }

    // row running top-2 per (mi, ni) stream — split by mi for ILP
    float tv0[2][4], tv1[2][4];
#pragma unroll
    for (int mi = 0; mi < 2; ++mi)
#pragma unroll
        for (int ni = 0; ni < 4; ++ni) { tv0[mi][ni] = NEG_INF_F; tv1[mi][ni] = NEG_INF_F; }

    const char* gbase = (const char*)(Bbf + ((size_t)colBase << 8));
    const floatx4 fzero = {0.f, 0.f, 0.f, 0.f};
    floatx4 acc[2][4];

#define STAGE(CIDX, BUFSEL) do {                                              \
        const char* gsrc_ = gbase + (size_t)(CIDX) * CHUNK_BYTES;             \
        char* bdst_ = smem + (BUFSEL) * CHUNK_BYTES;                          \
        _Pragma("unroll")                                                     \
        for (int r_ = 0; r_ < 4; ++r_) {                                      \
            int off_ = w * 4096 + r_ * 1024;                                  \
            __builtin_amdgcn_global_load_lds((gu32*)(gsrc_ + off_ + l * 16),  \
                                             (lu32*)(bdst_ + off_), 16, 0, 0);\
        }                                                                     \
    } while (0)

#define MERGE2(CIDX) do {                                                     \
        if (t < 64) {                                                         \
            float b0_ = NEG_INF_F, b1_ = NEG_INF_F, b2_ = NEG_INF_F;          \
            _Pragma("unroll")                                                 \
            for (int j_ = 0; j_ < 16; ++j_) {                                 \
                float2 v_ = colwave[(CIDX) & 1][t][j_];                       \
                float k_ = v_.x, h_;                                          \
                h_ = fmaxf(b0_, k_); k_ = fminf(b0_, k_); b0_ = h_;           \
                h_ = fmaxf(b1_, k_); k_ = fminf(b1_, k_); b1_ = h_;           \
                b2_ = fmaxf(b2_, k_);                                         \
                k_ = v_.y;                                                    \
                h_ = fmaxf(b0_, k_); k_ = fminf(b0_, k_); b0_ = h_;           \
                h_ = fmaxf(b1_, k_); k_ = fminf(b1_, k_); b1_ = h_;           \
                b2_ = fmaxf(b2_, k_);                                         \
            }                                                                 \
            int colG_ = colBase + (CIDX) * CHUNK + t;                         \
            cand_col[(size_t)(rt * 3 + 0) * NP + colG_] = __float_as_uint(b0_);\
            cand_col[(size_t)(rt * 3 + 1) * NP + colG_] = __float_as_uint(b1_);\
            cand_col[(size_t)(rt * 3 + 2) * NP + colG_] = __float_as_uint(b2_);\
        }                                                                     \
    } while (0)

    STAGE(0, 0);

    for (int c = 0; c < NCHUNK; ++c) {
        __syncthreads();   // B1: staging(c) ready; colwave[(c-1)&1] published
        if (c + 1 < NCHUNK) STAGE(c + 1, (c + 1) & 1);
        if (c > 0) MERGE2(c - 1);

#pragma unroll
        for (int sub = 0; sub < 2; ++sub) {
            const char* buf = smem + (c & 1) * CHUNK_BYTES + sub * 16384;

            // ---- COMPUTE: 64 MFMA into acc ----
            {
                __builtin_amdgcn_s_setprio(1);
                {
                    short8 a0 = *(const short8*)(buf + aoff[0]);
                    short8 a1 = *(const short8*)(buf + aoff[0] + 8192);
#pragma unroll
                    for (int ni = 0; ni < 4; ++ni) {
                        acc[0][ni] = __builtin_amdgcn_mfma_f32_16x16x32_bf16(a0, Bfr[ni][0], fzero, 0, 0, 0);
                        acc[1][ni] = __builtin_amdgcn_mfma_f32_16x16x32_bf16(a1, Bfr[ni][0], fzero, 0, 0, 0);
                    }
                }
#pragma unroll
                for (int kk = 1; kk < 8; ++kk) {
                    short8 a0 = *(const short8*)(buf + aoff[kk]);
                    short8 a1 = *(const short8*)(buf + aoff[kk] + 8192);
#pragma unroll
                    for (int ni = 0; ni < 4; ++ni) {
                        acc[0][ni] = __builtin_amdgcn_mfma_f32_16x16x32_bf16(a0, Bfr[ni][kk], acc[0][ni], 0, 0, 0);
                        acc[1][ni] = __builtin_amdgcn_mfma_f32_16x16x32_bf16(a1, Bfr[ni][kk], acc[1][ni], 0, 0, 0);
                    }
                }
                __builtin_amdgcn_s_setprio(0);
            }

            // ---- COL extract: per-lane sorted pair of 4 rows -> cbw[w] ----
            {
                const unsigned brb = ((unsigned)w << 6) | (unsigned)l15;
#pragma unroll
                for (int mi = 0; mi < 2; ++mi) {
#pragma unroll
                    for (int reg = 0; reg < 4; ++reg) {
                        unsigned k0 = (__float_as_uint(acc[mi][0][reg]) & 0xFFFFFE00u) | brb;
                        unsigned k1 = (__float_as_uint(acc[mi][1][reg]) & 0xFFFFFE00u) | (brb | 16u);
                        unsigned k2 = (__float_as_uint(acc[mi][2][reg]) & 0xFFFFFE00u) | (brb | 32u);
                        unsigned k3 = (__float_as_uint(acc[mi][3][reg]) & 0xFFFFFE00u) | (brb | 48u);
                        float f0 = __uint_as_float(k0), f1 = __uint_as_float(k1);
                        float f2 = __uint_as_float(k2), f3 = __uint_as_float(k3);
                        float h01 = fmaxf(f0, f1), l01 = fminf(f0, f1);
                        float h23 = fmaxf(f2, f3), l23 = fminf(f2, f3);
                        float hi = fmaxf(h01, h23);
                        float lo = fmaxf(fminf(h01, h23), fmaxf(l01, l23));
                        int colL = mi * 16 + lhi * 4 + reg;
                        cbw[w][colL * 17 + l15] = make_float2(hi, lo);
                    }
                }
            }

            // ---- ROW top-2 (21-bit key | (c*64 + sub*32 + col-local)) ----
            {
                const int cS = (c << 6) | (sub << 5);
#pragma unroll
                for (int mi = 0; mi < 2; ++mi) {
#pragma unroll
                    for (int reg = 0; reg < 4; ++reg) {
                        const int ib = (lhi * 4 + mi * 16 + reg) | cS;
#pragma unroll
                        for (int ni = 0; ni < 4; ++ni) {
                            int kb = (__float_as_int(acc[mi][ni][reg]) & (int)ROWKEY_MASK) | ib;
                            float fk = __int_as_float(kb);
                            float h = fmaxf(tv0[mi][ni], fk);
                            float lo2 = fminf(tv0[mi][ni], fk);
                            tv0[mi][ni] = h;
                            tv1[mi][ni] = fmaxf(tv1[mi][ni], lo2);
                        }
                    }
                }
            }

            // ---- wave merge (no barrier: same-wave DS ops in-order):
            //      2 lanes/col read 8 pairs each -> top-2 of 16 -> colwave ----
            {
                int colR = l >> 1, half = l & 1;
                const float2* src = &cbw[w][colR * 17 + half * 8];
                float a = NEG_INF_F, b = NEG_INF_F;
#pragma unroll
                for (int j = 0; j < 8; ++j) {
                    float2 v = src[j];
                    float t0 = fmaxf(a, v.x);
                    float t1 = fmaxf(fminf(a, v.x), fmaxf(b, v.y));
                    a = t0; b = t1;
                }
                colwave[c & 1][sub * 32 + colR][w * 2 + half] = make_float2(a, b);
            }
        }
    }
    __syncthreads();       // publishes colwave[(NCHUNK-1)&1]; cbw free
    MERGE2(NCHUNK - 1);
#undef STAGE
#undef MERGE2

    // ---- final row merge: 16 keys per row -> top-3 keys per split ----
    int4* mrg = (int4*)cbw;        // [512 rows][4 lhi] int4 = 32 KB (cbw is 35)
#pragma unroll
    for (int ni = 0; ni < 4; ++ni) {
        int rloc = w * 64 + ni * 16 + l15;
        int4 p;
        p.x = __float_as_int(tv0[0][ni]);
        p.y = __float_as_int(tv1[0][ni]);
        p.z = __float_as_int(tv0[1][ni]);
        p.w = __float_as_int(tv1[1][ni]);
        mrg[rloc * 4 + lhi] = p;
    }
    __syncthreads();
    {
        float b0 = NEG_INF_F, b1 = NEG_INF_F, b2 = NEG_INF_F;
#pragma unroll
        for (int q = 0; q < 4; ++q) {
            int4 p = mrg[t * 4 + q];
            int ks[4] = {p.x, p.y, p.z, p.w};
#pragma unroll
            for (int j = 0; j < 4; ++j) {
                float k = __int_as_float(ks[j]), h;
                h = fmaxf(b0, k); k = fminf(b0, k); b0 = h;
                h = fmaxf(b1, k); k = fminf(b1, k); b1 = h;
                b2 = fmaxf(b2, k);
            }
        }
        int rowG = rowBase + t;
        unsigned* o = cand_row + (size_t)rowG * 24 + split * 3;
        o[0] = __float_as_uint(b0);
        o[1] = __float_as_uint(b1);
        o[2] = __float_as_uint(b2);
    }
}

// ------------------------------------------------------------------
// mergecol PARALLEL: 4 threads/col over disjoint 24-slot subsets,
// each keeps top-6 (key,row) pairs; one thread merges 24 -> col6.
// ------------------------------------------------------------------
__global__ __launch_bounds__(256) void mergecol_kernel(
    const unsigned* __restrict__ cand_col, int* __restrict__ col6)
{
    __shared__ int2 pairs[64][4][6];   // 12 KB
    const int t = threadIdx.x;
    const int colL = t >> 2, g = t & 3;
    const int col = blockIdx.x * 64 + colL;

    float bk[6]; int br[6];
#pragma unroll
    for (int q = 0; q < 6; ++q) { bk[q] = NEG_INF_F; br[q] = 0; }
#pragma unroll 4
    for (int k = 0; k < NCOLSLOT / 4; ++k) {
        int s = g + (k << 2);
        unsigned ku = cand_col[(size_t)s * NP + col];
        float key = __uint_as_float(ku);
        int row = (s / 3) * ROWS + (int)(ku & 0x1FFu);
#pragma unroll
        for (int q = 0; q < 6; ++q) {
            bool gt = key > bk[q];
            float ek = gt ? bk[q] : key;
            int   er = gt ? br[q] : row;
            bk[q] = gt ? key : bk[q];
            br[q] = gt ? row : br[q];
            key = ek; row = er;
        }
    }
#pragma unroll
    for (int q = 0; q < 6; ++q)
        pairs[colL][g][q] = make_int2(__float_as_int(bk[q]), br[q]);
    __syncthreads();

    if (g == 0) {
        float mk[6]; int mr[6];
#pragma unroll
        for (int q = 0; q < 6; ++q) { mk[q] = NEG_INF_F; mr[q] = 0; }
#pragma unroll
        for (int gg = 0; gg < 4; ++gg) {
#pragma unroll
            for (int q2 = 0; q2 < 6; ++q2) {
                int2 p = pairs[colL][gg][q2];
                float key = __int_as_float(p.x);
                int row = p.y;
#pragma unroll
                for (int q = 0; q < 6; ++q) {
                    bool gt = key > mk[q];
                    float ek = gt ? mk[q] : key;
                    int   er = gt ? mr[q] : row;
                    mk[q] = gt ? key : mk[q];
                    mr[q] = gt ? row : mr[q];
                    key = ek; row = er;
                }
            }
        }
        int* o = col6 + (size_t)col * 6;
#pragma unroll
        for (int q = 0; q < 6; ++q) o[q] = mr[q];
    }
}

// ------------------------------------------------------------------
// rescore (FUSED): pass 0 = row rescore (threshold top-8 of 24 keys,
// exact fp32 top-2); pass 1 = col rescore (6 cands). Wave per job.
// ------------------------------------------------------------------
__global__ __launch_bounds__(256) void rescore_kernel(
    const float* __restrict__ AT, const float* __restrict__ BT,
    const unsigned* __restrict__ cand_row, const int* __restrict__ col6,
    float4* __restrict__ final12,
    int* __restrict__ nn21, float* __restrict__ ratio21)
{
    const int t = threadIdx.x;
    const int w = t >> 6, l = t & 63;
    const int gjob = blockIdx.x * 4 + w;   // 0..32767
    const int pass = gjob >> 14;
    const int id = gjob & (NP - 1);

    if (pass == 0) {
        const int row = id;
        float4 rv = *(const float4*)(AT + ((size_t)row << 8) + l * 4);
        const unsigned* __restrict__ cl = cand_row + (size_t)row * 24;

        float t8[8];
#pragma unroll
        for (int q = 0; q < 8; ++q) t8[q] = NEG_INF_F;
#pragma unroll
        for (int s = 0; s < 24; ++s) {
            float k = __uint_as_float(cl[s]);
#pragma unroll
            for (int q = 0; q < 8; ++q) {
                float h = fmaxf(t8[q], k);
                k = fminf(t8[q], k);
                t8[q] = h;
            }
        }
        const float thr = t8[7];

        float v0 = -4.f, v1 = -4.f; int i0 = 0x7fffffff, i1 = 0x7fffffff;
        int taken = 0;
        for (int s = 0; s < 24; ++s) {
            unsigned ku = cl[s];
            float kf = __uint_as_float(ku);
            if (kf >= thr && taken < 8) {      // wave-uniform
                ++taken;
                int idx = (s / 3) * CPS + (int)(ku & 0x7FFu);
                float4 cv = *(const float4*)(BT + ((size_t)idx << 8) + l * 4);
                float d = rv.x * cv.x;
                d = fmaf(rv.y, cv.y, d);
                d = fmaf(rv.z, cv.z, d);
                d = fmaf(rv.w, cv.w, d);
#pragma unroll
                for (int m = 1; m < 64; m <<= 1) d += __shfl_xor(d, m, 64);
                if (d > v0 || (d == v0 && idx < i0)) {
                    v1 = v0; i1 = i0; v0 = d; i0 = idx;
                } else if (d > v1 || (d == v1 && idx < i1)) {
                    v1 = d; i1 = idx;
                }
            }
        }
        if (l == 0) {
            float4 r; r.x = v0; r.y = v1;
            r.z = __int_as_float(i0); r.w = __int_as_float(i1);
            final12[row] = r;
        }
    } else {
        const int col = id;
        float4 rv = *(const float4*)(BT + ((size_t)col << 8) + l * 4);
        float v0 = -4.f, v1 = -4.f; int i0 = 0x7fffffff, i1 = 0x7fffffff;
        const int* __restrict__ cl = col6 + (size_t)col * 6;
#pragma unroll
        for (int j = 0; j < 6; ++j) {
            int idx = cl[j];
            float4 cv = *(const float4*)(AT + ((size_t)idx << 8) + l * 4);
            float d = rv.x * cv.x;
            d = fmaf(rv.y, cv.y, d);
            d = fmaf(rv.z, cv.z, d);
            d = fmaf(rv.w, cv.w, d);
#pragma unroll
            for (int m = 1; m < 64; m <<= 1) d += __shfl_xor(d, m, 64);
            if (d > v0 || (d == v0 && idx < i0)) {
                v1 = v0; i1 = i0; v0 = d; i0 = idx;
            } else if (d > v1 || (d == v1 && idx < i1)) {
                v1 = d; i1 = idx;
            }
        }
        if (l == 0) {
            nn21[col] = i0;
            float d0 = sqrtf(fmaxf(2.f - 2.f * v0, 1e-12f));
            float d1 = sqrtf(fmaxf(2.f - 2.f * v1, 1e-12f));
            ratio21[col] = d0 / (d1 + EPSF);
        }
    }
}

// ------------------------------------------------------------------
// final: mutual check, ratio test, border mask
// ------------------------------------------------------------------
__global__ void final_kernel(const float4* __restrict__ final12,
                             const int* __restrict__ nn21,
                             const float* __restrict__ ratio21,
                             float* __restrict__ out) {
    int i = blockIdx.x * blockDim.x + threadIdx.x;  // 0..16383
    float4 a = final12[i];
    float d0 = sqrtf(fmaxf(2.f - 2.f * a.x, 1e-12f));
    float d1 = sqrtf(fmaxf(2.f - 2.f * a.y, 1e-12f));
    int nn = __float_as_int(a.z);
    float r12 = d0 / (d1 + EPSF);
    bool mutual = (nn21[nn] == i);
    float r = fmaxf(r12, ratio21[nn]);
    int xA = i & (WDIM - 1), yA = i >> 7;
    int xB = nn & (WDIM - 1), yB = nn >> 7;
    bool border = (xA == 0) || (xA == WDIM - 1) || (yA == 0) || (yA == WDIM - 1) ||
                  (xB == 0) || (xB == WDIM - 1) || (yB == 0) || (yB == WDIM - 1);
    bool valid = mutual && (r < 0.95f) && !border;
    out[2 * i]       = valid ? d0 : 0.f;
    out[2 * i + 1]   = valid ? d1 : 0.f;
    out[2 * NP + i]  = (float)nn;
    out[3 * NP + i]  = valid ? 1.f : 0.f;
}

extern "C" void kernel_launch(void* const* d_in, const int* in_sizes, int n_in,
                              void* d_out, int out_size, void* d_ws, size_t ws_size,
                              hipStream_t stream) {
    (void)in_sizes; (void)n_in; (void)out_size; (void)ws_size;
    const float* A = (const float*)d_in[0];
    const float* B = (const float*)d_in[1];
    float* out = (float*)d_out;

    char* ws = (char*)d_ws;
    float* AT = (float*)ws;                                          // 16 MB
    float* BT = AT + (size_t)NP * CH;                                // 16 MB
    unsigned short* Abf = (unsigned short*)(BT + (size_t)NP * CH);   // 8 MB
    unsigned short* Bbf = Abf + (size_t)NP * CH;                     // 8 MB
    unsigned* cand_row = (unsigned*)(Bbf + (size_t)NP * CH);         // 1.5 MB
    unsigned* cand_col = cand_row + (size_t)NP * 24;                 // 6.3 MB
    int* col6 = (int*)(cand_col + (size_t)NCOLSLOT * NP);            // 0.4 MB
    float4* final12 = (float4*)(col6 + (size_t)NP * 6);              // 256 KB
    int* nn21 = (int*)(final12 + NP);                                // 64 KB
    float* ratio21 = (float*)(nn21 + NP);                            // 64 KB

    prep_kernel<<<512, 256, 0, stream>>>(A, B, AT, BT, Abf, Bbf);
    simk_kernel<<<NRT * SPLITS, 512, 0, stream>>>(Abf, Bbf, cand_row, cand_col);
    mergecol_kernel<<<NP / 64, 256, 0, stream>>>(cand_col, col6);
    rescore_kernel<<<NP / 2, 256, 0, stream>>>(AT, BT, cand_row, col6,
                                               final12, nn21, ratio21);
    final_kernel<<<NP / 256, 256, 0, stream>>>(final12, nn21, ratio21, out);
}

// Round 20
// 237.742 us; speedup vs baseline: 2.3932x; 1.0224x over previous
//
#include <hip/hip_runtime.h>
#include <math.h>

#define NP 16384      // pixels per map (128*128)
#define CH 256        // channels (K)
#define WDIM 128
#define EPSF 1e-8f

#define CHUNK 64                     // cols per staged chunk (2 sub-batches of 32)
#define SPLITS 8
#define CPS (NP / SPLITS)            // 2048 cols per split
#define NCHUNK (CPS / CHUNK)         // 32
#define ROWS 512                     // rows per block (8 waves x 64)
#define NRT (NP / ROWS)              // 32 row tiles
#define CHUNK_BYTES (CHUNK * CH * 2) // 32768
#define NCOLSLOT (NRT * 3)           // 96 col-candidate slots per column

typedef short short8 __attribute__((ext_vector_type(8)));
typedef float floatx4 __attribute__((ext_vector_type(4)));

typedef __attribute__((address_space(1))) const unsigned int gu32;
typedef __attribute__((address_space(3))) unsigned int lu32;

#define NEG_INF_F __int_as_float(0xFF800000)
#define ROWKEY_MASK 0xFFFFF800u      // 21-bit sim | 11-bit local col

// median-of-3, single VALU op (sorted-insert: b_i' = med3(b_{i-1}, b_i, k))
__device__ __forceinline__ float med3f(float a, float b, float c) {
    float r;
    asm("v_med3_f32 %0, %1, %2, %3" : "=v"(r) : "v"(a), "v"(b), "v"(c));
    return r;
}

// ------------------------------------------------------------------
// prep: per-pixel 1/||d||, fp32 normalized transposed [pix][256],
// bf16 normalized swizzled (element ch stored at ch ^ ((pix&7)<<3))
// ------------------------------------------------------------------
__global__ __launch_bounds__(256) void prep_kernel(
    const float* __restrict__ A, const float* __restrict__ B,
    float* __restrict__ AT, float* __restrict__ BT,
    unsigned short* __restrict__ Abf, unsigned short* __restrict__ Bbf)
{
    __shared__ float tile[64 * 257];
    __shared__ float rnv[64];
    const int bid = blockIdx.x;
    const float* __restrict__ src = (bid < 256) ? A : B;
    float* __restrict__ dstT = (bid < 256) ? AT : BT;
    unsigned short* __restrict__ dstb = (bid < 256) ? Abf : Bbf;
    const int pixBase = (bid & 255) * 64;
    const int t = threadIdx.x;

    for (int k = 0; k < 64 * 256; k += 256) {
        int idx = k + t;
        int p = idx & 63;
        int c = idx >> 6;
        tile[p * 257 + c] = src[(size_t)c * NP + pixBase + p];
    }
    __syncthreads();
    if (t < 64) {
        float s = 0.f;
        for (int c = 0; c < 256; ++c) { float v = tile[t * 257 + c]; s = fmaf(v, v, s); }
        rnv[t] = 1.0f / sqrtf(s);
    }
    __syncthreads();
    for (int k = 0; k < 64 * 256; k += 256) {
        int idx = k + t;
        int p = idx >> 8;
        int c = idx & 255;
        dstT[((size_t)(pixBase + p) << 8) + c] = tile[p * 257 + c] * rnv[p];
    }
    for (int k = 0; k < 64 * 128; k += 256) {
        int idx = k + t;
        int p = idx >> 7;
        int c2 = (idx & 127) * 2;
        float rn = rnv[p];
        float v0 = tile[p * 257 + c2] * rn;
        float v1 = tile[p * 257 + c2 + 1] * rn;
        unsigned u0 = __float_as_uint(v0); u0 = (u0 + 0x7fffu + ((u0 >> 16) & 1u)) >> 16;
        unsigned u1 = __float_as_uint(v1); u1 = (u1 + 0x7fffu + ((u1 >> 16) & 1u)) >> 16;
        unsigned sw = ((unsigned)(p & 7)) << 3;
        int e = ((pixBase + p) << 8) + (c2 ^ (int)sw);
        *(unsigned*)(dstb + e) = (u0 & 0xffffu) | (u1 << 16);
    }
}

// ------------------------------------------------------------------
// simk ONE-PASS, 512-row blocks, CHUNK=64 (two 32-col sub-batches),
// R19 structure + v_med3_f32 sorted-inserts (row top-2: 3->2 ops/val;
// col extract sec-of-4 via med3; MERGE2 top-3: 7->4 ops/key).
// ------------------------------------------------------------------
__global__ __launch_bounds__(512, 2) void simk_kernel(
    const unsigned short* __restrict__ Abf, const unsigned short* __restrict__ Bbf,
    unsigned* __restrict__ cand_row, unsigned* __restrict__ cand_col)
{
    __shared__ __align__(16) char smem[2 * CHUNK_BYTES];      // 64 KB staging
    __shared__ __align__(16) float2 cbw[8][32 * 17 + 4];      // 35 KB wave-private
    __shared__ __align__(16) float2 colwave[2][64][17];       // 17.4 KB dbuf
    const int bid = blockIdx.x;
    const int rt = bid >> 3;          // 0..31
    const int split = bid & 7;
    const int t = threadIdx.x;        // 0..511
    const int w = t >> 6;             // 0..7
    const int l = t & 63;
    const int l15 = l & 15, lhi = l >> 4;
    const int rowBase = rt * ROWS;
    const int colBase = split * CPS;

    // --- row-descriptor fragments (B-operand) from A, pinned ---
    short8 Bfr[4][8];
#pragma unroll
    for (int ni = 0; ni < 4; ++ni) {
        int pix = rowBase + w * 64 + ni * 16 + l15;
        const unsigned short* pr = Abf + ((size_t)pix << 8);
        int sw = (pix & 7) << 3;
#pragma unroll
        for (int kk = 0; kk < 8; ++kk) {
            int ke = kk * 32 + lhi * 8;
            Bfr[ni][kk] = *(const short8*)(pr + (ke ^ sw));
        }
    }
#pragma unroll
    for (int ni = 0; ni < 4; ++ni)
#pragma unroll
        for (int kk = 0; kk < 8; ++kk)
            asm volatile("" : "+v"(Bfr[ni][kk]));

    // --- LDS byte offsets for A-operand frags (mi=0; mi=1 is +8192) ---
    int aoff[8];
    {
        int cp = l15;
        int sw = (cp & 7) << 3;
#pragma unroll
        for (int kk = 0; kk < 8; ++kk) {
            int ke = kk * 32 + lhi * 8;
            aoff[kk] = (cp * 256 + (ke ^ sw)) * 2;
        }
    }

    // row running top-2 per (mi, ni) stream — split by mi for ILP
    float tv0[2][4], tv1[2][4];
#pragma unroll
    for (int mi = 0; mi < 2; ++mi)
#pragma unroll
        for (int ni = 0; ni < 4; ++ni) { tv0[mi][ni] = NEG_INF_F; tv1[mi][ni] = NEG_INF_F; }

    const char* gbase = (const char*)(Bbf + ((size_t)colBase << 8));
    const floatx4 fzero = {0.f, 0.f, 0.f, 0.f};
    floatx4 acc[2][4];

#define STAGE(CIDX, BUFSEL) do {                                              \
        const char* gsrc_ = gbase + (size_t)(CIDX) * CHUNK_BYTES;             \
        char* bdst_ = smem + (BUFSEL) * CHUNK_BYTES;                          \
        _Pragma("unroll")                                                     \
        for (int r_ = 0; r_ < 4; ++r_) {                                      \
            int off_ = w * 4096 + r_ * 1024;                                  \
            __builtin_amdgcn_global_load_lds((gu32*)(gsrc_ + off_ + l * 16),  \
                                             (lu32*)(bdst_ + off_), 16, 0, 0);\
        }                                                                     \
    } while (0)

#define MERGE2(CIDX) do {                                                     \
        if (t < 64) {                                                         \
            float b0_ = NEG_INF_F, b1_ = NEG_INF_F, b2_ = NEG_INF_F;          \
            _Pragma("unroll")                                                 \
            for (int j_ = 0; j_ < 16; ++j_) {                                 \
                float2 v_ = colwave[(CIDX) & 1][t][j_];                       \
                b2_ = fmaxf(b2_, fminf(b1_, v_.x));                           \
                b1_ = med3f(b0_, b1_, v_.x);                                  \
                b0_ = fmaxf(b0_, v_.x);                                       \
                b2_ = fmaxf(b2_, fminf(b1_, v_.y));                           \
                b1_ = med3f(b0_, b1_, v_.y);                                  \
                b0_ = fmaxf(b0_, v_.y);                                       \
            }                                                                 \
            int colG_ = colBase + (CIDX) * CHUNK + t;                         \
            cand_col[(size_t)(rt * 3 + 0) * NP + colG_] = __float_as_uint(b0_);\
            cand_col[(size_t)(rt * 3 + 1) * NP + colG_] = __float_as_uint(b1_);\
            cand_col[(size_t)(rt * 3 + 2) * NP + colG_] = __float_as_uint(b2_);\
        }                                                                     \
    } while (0)

    STAGE(0, 0);

    for (int c = 0; c < NCHUNK; ++c) {
        __syncthreads();   // B1: staging(c) ready; colwave[(c-1)&1] published
        if (c + 1 < NCHUNK) STAGE(c + 1, (c + 1) & 1);
        if (c > 0) MERGE2(c - 1);

#pragma unroll
        for (int sub = 0; sub < 2; ++sub) {
            const char* buf = smem + (c & 1) * CHUNK_BYTES + sub * 16384;

            // ---- COMPUTE: 64 MFMA into acc ----
            {
                __builtin_amdgcn_s_setprio(1);
                {
                    short8 a0 = *(const short8*)(buf + aoff[0]);
                    short8 a1 = *(const short8*)(buf + aoff[0] + 8192);
#pragma unroll
                    for (int ni = 0; ni < 4; ++ni) {
                        acc[0][ni] = __builtin_amdgcn_mfma_f32_16x16x32_bf16(a0, Bfr[ni][0], fzero, 0, 0, 0);
                        acc[1][ni] = __builtin_amdgcn_mfma_f32_16x16x32_bf16(a1, Bfr[ni][0], fzero, 0, 0, 0);
                    }
                }
#pragma unroll
                for (int kk = 1; kk < 8; ++kk) {
                    short8 a0 = *(const short8*)(buf + aoff[kk]);
                    short8 a1 = *(const short8*)(buf + aoff[kk] + 8192);
#pragma unroll
                    for (int ni = 0; ni < 4; ++ni) {
                        acc[0][ni] = __builtin_amdgcn_mfma_f32_16x16x32_bf16(a0, Bfr[ni][kk], acc[0][ni], 0, 0, 0);
                        acc[1][ni] = __builtin_amdgcn_mfma_f32_16x16x32_bf16(a1, Bfr[ni][kk], acc[1][ni], 0, 0, 0);
                    }
                }
                __builtin_amdgcn_s_setprio(0);
            }

            // ---- COL extract: per-lane sorted pair of 4 rows -> cbw[w] ----
            {
                const unsigned brb = ((unsigned)w << 6) | (unsigned)l15;
#pragma unroll
                for (int mi = 0; mi < 2; ++mi) {
#pragma unroll
                    for (int reg = 0; reg < 4; ++reg) {
                        unsigned k0 = (__float_as_uint(acc[mi][0][reg]) & 0xFFFFFE00u) | brb;
                        unsigned k1 = (__float_as_uint(acc[mi][1][reg]) & 0xFFFFFE00u) | (brb | 16u);
                        unsigned k2 = (__float_as_uint(acc[mi][2][reg]) & 0xFFFFFE00u) | (brb | 32u);
                        unsigned k3 = (__float_as_uint(acc[mi][3][reg]) & 0xFFFFFE00u) | (brb | 48u);
                        float f0 = __uint_as_float(k0), f1 = __uint_as_float(k1);
                        float f2 = __uint_as_float(k2), f3 = __uint_as_float(k3);
                        float h01 = fmaxf(f0, f1), l01 = fminf(f0, f1);
                        float h23 = fmaxf(f2, f3), l23 = fminf(f2, f3);
                        float hi = fmaxf(h01, h23);
                        float lo = med3f(h01, h23, fmaxf(l01, l23));
                        int colL = mi * 16 + lhi * 4 + reg;
                        cbw[w][colL * 17 + l15] = make_float2(hi, lo);
                    }
                }
            }

            // ---- ROW top-2 via med3 insert (2 ops/value) ----
            {
                const int cS = (c << 6) | (sub << 5);
#pragma unroll
                for (int mi = 0; mi < 2; ++mi) {
#pragma unroll
                    for (int reg = 0; reg < 4; ++reg) {
                        const int ib = (lhi * 4 + mi * 16 + reg) | cS;
#pragma unroll
                        for (int ni = 0; ni < 4; ++ni) {
                            int kb = (__float_as_int(acc[mi][ni][reg]) & (int)ROWKEY_MASK) | ib;
                            float fk = __int_as_float(kb);
                            tv1[mi][ni] = med3f(tv0[mi][ni], tv1[mi][ni], fk);
                            tv0[mi][ni] = fmaxf(tv0[mi][ni], fk);
                        }
                    }
                }
            }

            // ---- wave merge (no barrier: same-wave DS ops in-order):
            //      2 lanes/col read 8 pairs each -> top-2 of 16 -> colwave ----
            {
                int colR = l >> 1, half = l & 1;
                const float2* src = &cbw[w][colR * 17 + half * 8];
                float a = NEG_INF_F, b = NEG_INF_F;
#pragma unroll
                for (int j = 0; j < 8; ++j) {
                    float2 v = src[j];
                    float t0 = fmaxf(a, v.x);
                    float t1 = fmaxf(fminf(a, v.x), fmaxf(b, v.y));
                    a = t0; b = t1;
                }
                colwave[c & 1][sub * 32 + colR][w * 2 + half] = make_float2(a, b);
            }
        }
    }
    __syncthreads();       // publishes colwave[(NCHUNK-1)&1]; cbw free
    MERGE2(NCHUNK - 1);
#undef STAGE
#undef MERGE2

    // ---- final row merge: 16 keys per row -> top-3 keys per split ----
    int4* mrg = (int4*)cbw;        // [512 rows][4 lhi] int4 = 32 KB (cbw is 35)
#pragma unroll
    for (int ni = 0; ni < 4; ++ni) {
        int rloc = w * 64 + ni * 16 + l15;
        int4 p;
        p.x = __float_as_int(tv0[0][ni]);
        p.y = __float_as_int(tv1[0][ni]);
        p.z = __float_as_int(tv0[1][ni]);
        p.w = __float_as_int(tv1[1][ni]);
        mrg[rloc * 4 + lhi] = p;
    }
    __syncthreads();
    {
        float b0 = NEG_INF_F, b1 = NEG_INF_F, b2 = NEG_INF_F;
#pragma unroll
        for (int q = 0; q < 4; ++q) {
            int4 p = mrg[t * 4 + q];
            int ks[4] = {p.x, p.y, p.z, p.w};
#pragma unroll
            for (int j = 0; j < 4; ++j) {
                float k = __int_as_float(ks[j]);
                b2 = fmaxf(b2, fminf(b1, k));
                b1 = med3f(b0, b1, k);
                b0 = fmaxf(b0, k);
            }
        }
        int rowG = rowBase + t;
        unsigned* o = cand_row + (size_t)rowG * 24 + split * 3;
        o[0] = __float_as_uint(b0);
        o[1] = __float_as_uint(b1);
        o[2] = __float_as_uint(b2);
    }
}

// ------------------------------------------------------------------
// mergecol PARALLEL: 4 threads/col over disjoint 24-slot subsets,
// each keeps top-6 (key,row) pairs; one thread merges 24 -> col6.
// (conditional-swap kept: payload row must travel with key)
// ------------------------------------------------------------------
__global__ __launch_bounds__(256) void mergecol_kernel(
    const unsigned* __restrict__ cand_col, int* __restrict__ col6)
{
    __shared__ int2 pairs[64][4][6];   // 12 KB
    const int t = threadIdx.x;
    const int colL = t >> 2, g = t & 3;
    const int col = blockIdx.x * 64 + colL;

    float bk[6]; int br[6];
#pragma unroll
    for (int q = 0; q < 6; ++q) { bk[q] = NEG_INF_F; br[q] = 0; }
#pragma unroll 4
    for (int k = 0; k < NCOLSLOT / 4; ++k) {
        int s = g + (k << 2);
        unsigned ku = cand_col[(size_t)s * NP + col];
        float key = __uint_as_float(ku);
        int row = (s / 3) * ROWS + (int)(ku & 0x1FFu);
#pragma unroll
        for (int q = 0; q < 6; ++q) {
            bool gt = key > bk[q];
            float ek = gt ? bk[q] : key;
            int   er = gt ? br[q] : row;
            bk[q] = gt ? key : bk[q];
            br[q] = gt ? row : br[q];
            key = ek; row = er;
        }
    }
#pragma unroll
    for (int q = 0; q < 6; ++q)
        pairs[colL][g][q] = make_int2(__float_as_int(bk[q]), br[q]);
    __syncthreads();

    if (g == 0) {
        float mk[6]; int mr[6];
#pragma unroll
        for (int q = 0; q < 6; ++q) { mk[q] = NEG_INF_F; mr[q] = 0; }
#pragma unroll
        for (int gg = 0; gg < 4; ++gg) {
#pragma unroll
            for (int q2 = 0; q2 < 6; ++q2) {
                int2 p = pairs[colL][gg][q2];
                float key = __int_as_float(p.x);
                int row = p.y;
#pragma unroll
                for (int q = 0; q < 6; ++q) {
                    bool gt = key > mk[q];
                    float ek = gt ? mk[q] : key;
                    int   er = gt ? mr[q] : row;
                    mk[q] = gt ? key : mk[q];
                    mr[q] = gt ? row : mr[q];
                    key = ek; row = er;
                }
            }
        }
        int* o = col6 + (size_t)col * 6;
#pragma unroll
        for (int q = 0; q < 6; ++q) o[q] = mr[q];
    }
}

// ------------------------------------------------------------------
// rescore (FUSED): pass 0 = row rescore (med3 threshold top-8 of 24
// keys, exact fp32 top-2); pass 1 = col rescore (6 cands).
// ------------------------------------------------------------------
__global__ __launch_bounds__(256) void rescore_kernel(
    const float* __restrict__ AT, const float* __restrict__ BT,
    const unsigned* __restrict__ cand_row, const int* __restrict__ col6,
    float4* __restrict__ final12,
    int* __restrict__ nn21, float* __restrict__ ratio21)
{
    const int t = threadIdx.x;
    const int w = t >> 6, l = t & 63;
    const int gjob = blockIdx.x * 4 + w;   // 0..32767
    const int pass = gjob >> 14;
    const int id = gjob & (NP - 1);

    if (pass == 0) {
        const int row = id;
        float4 rv = *(const float4*)(AT + ((size_t)row << 8) + l * 4);
        const unsigned* __restrict__ cl = cand_row + (size_t)row * 24;

        float t8[8];
#pragma unroll
        for (int q = 0; q < 8; ++q) t8[q] = NEG_INF_F;
#pragma unroll
        for (int s = 0; s < 24; ++s) {
            float k = __uint_as_float(cl[s]);
#pragma unroll
            for (int q = 7; q >= 1; --q)
                t8[q] = med3f(t8[q - 1], t8[q], k);
            t8[0] = fmaxf(t8[0], k);
        }
        const float thr = t8[7];

        float v0 = -4.f, v1 = -4.f; int i0 = 0x7fffffff, i1 = 0x7fffffff;
        int taken = 0;
        for (int s = 0; s < 24; ++s) {
            unsigned ku = cl[s];
            float kf = __uint_as_float(ku);
            if (kf >= thr && taken < 8) {      // wave-uniform
                ++taken;
                int idx = (s / 3) * CPS + (int)(ku & 0x7FFu);
                float4 cv = *(const float4*)(BT + ((size_t)idx << 8) + l * 4);
                float d = rv.x * cv.x;
                d = fmaf(rv.y, cv.y, d);
                d = fmaf(rv.z, cv.z, d);
                d = fmaf(rv.w, cv.w, d);
#pragma unroll
                for (int m = 1; m < 64; m <<= 1) d += __shfl_xor(d, m, 64);
                if (d > v0 || (d == v0 && idx < i0)) {
                    v1 = v0; i1 = i0; v0 = d; i0 = idx;
                } else if (d > v1 || (d == v1 && idx < i1)) {
                    v1 = d; i1 = idx;
                }
            }
        }
        if (l == 0) {
            float4 r; r.x = v0; r.y = v1;
            r.z = __int_as_float(i0); r.w = __int_as_float(i1);
            final12[row] = r;
        }
    } else {
        const int col = id;
        float4 rv = *(const float4*)(BT + ((size_t)col << 8) + l * 4);
        float v0 = -4.f, v1 = -4.f; int i0 = 0x7fffffff, i1 = 0x7fffffff;
        const int* __restrict__ cl = col6 + (size_t)col * 6;
#pragma unroll
        for (int j = 0; j < 6; ++j) {
            int idx = cl[j];
            float4 cv = *(const float4*)(AT + ((size_t)idx << 8) + l * 4);
            float d = rv.x * cv.x;
            d = fmaf(rv.y, cv.y, d);
            d = fmaf(rv.z, cv.z, d);
            d = fmaf(rv.w, cv.w, d);
#pragma unroll
            for (int m = 1; m < 64; m <<= 1) d += __shfl_xor(d, m, 64);
            if (d > v0 || (d == v0 && idx < i0)) {
                v1 = v0; i1 = i0; v0 = d; i0 = idx;
            } else if (d > v1 || (d == v1 && idx < i1)) {
                v1 = d; i1 = idx;
            }
        }
        if (l == 0) {
            nn21[col] = i0;
            float d0 = sqrtf(fmaxf(2.f - 2.f * v0, 1e-12f));
            float d1 = sqrtf(fmaxf(2.f - 2.f * v1, 1e-12f));
            ratio21[col] = d0 / (d1 + EPSF);
        }
    }
}

// ------------------------------------------------------------------
// final: mutual check, ratio test, border mask
// ------------------------------------------------------------------
__global__ void final_kernel(const float4* __restrict__ final12,
                             const int* __restrict__ nn21,
                             const float* __restrict__ ratio21,
                             float* __restrict__ out) {
    int i = blockIdx.x * blockDim.x + threadIdx.x;  // 0..16383
    float4 a = final12[i];
    float d0 = sqrtf(fmaxf(2.f - 2.f * a.x, 1e-12f));
    float d1 = sqrtf(fmaxf(2.f - 2.f * a.y, 1e-12f));
    int nn = __float_as_int(a.z);
    float r12 = d0 / (d1 + EPSF);
    bool mutual = (nn21[nn] == i);
    float r = fmaxf(r12, ratio21[nn]);
    int xA = i & (WDIM - 1), yA = i >> 7;
    int xB = nn & (WDIM - 1), yB = nn >> 7;
    bool border = (xA == 0) || (xA == WDIM - 1) || (yA == 0) || (yA == WDIM - 1) ||
                  (xB == 0) || (xB == WDIM - 1) || (yB == 0) || (yB == WDIM - 1);
    bool valid = mutual && (r < 0.95f) && !border;
    out[2 * i]       = valid ? d0 : 0.f;
    out[2 * i + 1]   = valid ? d1 : 0.f;
    out[2 * NP + i]  = (float)nn;
    out[3 * NP + i]  = valid ? 1.f : 0.f;
}

extern "C" void kernel_launch(void* const* d_in, const int* in_sizes, int n_in,
                              void* d_out, int out_size, void* d_ws, size_t ws_size,
                              hipStream_t stream) {
    (void)in_sizes; (void)n_in; (void)out_size; (void)ws_size;
    const float* A = (const float*)d_in[0];
    const float* B = (const float*)d_in[1];
    float* out = (float*)d_out;

    char* ws = (char*)d_ws;
    float* AT = (float*)ws;                                          // 16 MB
    float* BT = AT + (size_t)NP * CH;                                // 16 MB
    unsigned short* Abf = (unsigned short*)(BT + (size_t)NP * CH);   // 8 MB
    unsigned short* Bbf = Abf + (size_t)NP * CH;                     // 8 MB
    unsigned* cand_row = (unsigned*)(Bbf + (size_t)NP * CH);         // 1.5 MB
    unsigned* cand_col = cand_row + (size_t)NP * 24;                 // 6.3 MB
    int* col6 = (int*)(cand_col + (size_t)NCOLSLOT * NP);            // 0.4 MB
    float4* final12 = (float4*)(col6 + (size_t)NP * 6);              // 256 KB
    int* nn21 = (int*)(final12 + NP);                                // 64 KB
    float* ratio21 = (float*)(nn21 + NP);                            // 64 KB

    prep_kernel<<<512, 256, 0, stream>>>(A, B, AT, BT, Abf, Bbf);
    simk_kernel<<<NRT * SPLITS, 512, 0, stream>>>(Abf, Bbf, cand_row, cand_col);
    mergecol_kernel<<<NP / 64, 256, 0, stream>>>(cand_col, col6);
    rescore_kernel<<<NP / 2, 256, 0, stream>>>(AT, BT, cand_row, col6,
                                               final12, nn21, ratio21);
    final_kernel<<<NP / 256, 256, 0, stream>>>(final12, nn21, ratio21, out);
}